// Round 4
// baseline (317.408 us; speedup 1.0000x reference)
//
#include <hip/hip_runtime.h>
#include <hip/hip_fp8.h>
#include <math.h>

#define NN 3072
#define NU 1024
#define NI 2048
#define DD 128
#define BB 8192
#define GAMMA_F 0.2f

#define SCALE_A 524288.0f                // 2^19
#define F8SCALE2 1.9073486328125e-06f    // 2^-19  (C*2^38 -> A2*2^19 for fp8)
#define DESCALE38 3.637978807091713e-12f // 2^-38  (C -> true A^k values)

// packed fp8 layout: [k/64][row][k%64]; one k-block = NN rows x 64 B
#define KBLK ((size_t)NN * 64)

typedef __attribute__((ext_vector_type(4))) float f32x4;
typedef __attribute__((ext_vector_type(16))) float f32x16;
typedef __attribute__((ext_vector_type(4))) int i32x4;
typedef __attribute__((ext_vector_type(8))) int i32x8;

static __device__ inline unsigned short bf16bits(float x) {
  union { unsigned u; float f; } cv;
  cv.f = x;
  unsigned r = cv.u + 0x7fff + ((cv.u >> 16) & 1);  // RNE
  return (unsigned short)(r >> 16);
}

// pack 4 floats -> 4 fp8 e4m3 (OCP) bytes
static __device__ inline unsigned pk4_f8(float a, float b, float c, float d) {
#if defined(__has_builtin)
#if __has_builtin(__builtin_amdgcn_cvt_pk_fp8_f32)
  int p = __builtin_amdgcn_cvt_pk_fp8_f32(a, b, 0, false);
  p = __builtin_amdgcn_cvt_pk_fp8_f32(c, d, p, true);
  return (unsigned)p;
#else
  return (unsigned)__hip_fp8_e4m3(a).__x | ((unsigned)__hip_fp8_e4m3(b).__x << 8) |
         ((unsigned)__hip_fp8_e4m3(c).__x << 16) |
         ((unsigned)__hip_fp8_e4m3(d).__x << 24);
#endif
#else
  return (unsigned)__hip_fp8_e4m3(a).__x | ((unsigned)__hip_fp8_e4m3(b).__x << 8) |
         ((unsigned)__hip_fp8_e4m3(c).__x << 16) |
         ((unsigned)__hip_fp8_e4m3(d).__x << 24);
#endif
}

static __device__ inline void atomAddF(float* p, float v) {
#if defined(__has_builtin)
#if __has_builtin(__builtin_amdgcn_global_atomic_fadd_f32)
  __builtin_amdgcn_global_atomic_fadd_f32(
      (__attribute__((address_space(1))) float*)p, v);
#else
  unsafeAtomicAdd(p, v);
#endif
#else
  unsafeAtomicAdd(p, v);
#endif
}

static __device__ inline float block_sum(float s, float* red4) {
  int tid = threadIdx.x;
  for (int off = 32; off; off >>= 1) s += __shfl_down(s, off, 64);
  if ((tid & 63) == 0) red4[tid >> 6] = s;
  __syncthreads();
  return red4[0] + red4[1] + red4[2] + red4[3];
}

static __device__ inline float row_dot_f32(const float* __restrict__ a,
                                           const float* __restrict__ b,
                                           float* red4) {
  const float4* ap = (const float4*)a;
  const float4* bp = (const float4*)b;
  float s = 0.f;
  for (int j = threadIdx.x; j < NN / 4; j += 256) {
    float4 x = ap[j], y = bp[j];
    s += x.x * y.x + x.y * y.y + x.z * y.z + x.w * y.w;
  }
  return block_sum(s, red4);
}

// ---------------------------------------------------------------------------
// topk loaders: fill f[48] with this row's values (one wave, 48 vals/lane).
static __device__ inline void load48_bf(const unsigned short* __restrict__ b0,
                                        int parts, int row, int lane,
                                        float* f) {
  const uint4* r0 = (const uint4*)(b0 + (size_t)row * NN);
#pragma unroll
  for (int j = 0; j < 6; ++j) {
    uint4 q = r0[lane + j * 64];
    unsigned uu[4] = {q.x, q.y, q.z, q.w};
#pragma unroll
    for (int e = 0; e < 4; ++e) {
      f[j * 8 + e * 2] = __uint_as_float(uu[e] << 16);
      f[j * 8 + e * 2 + 1] = __uint_as_float(uu[e] & 0xffff0000u);
    }
  }
  for (int p = 1; p < parts; ++p) {
    const uint4* rp = (const uint4*)(b0 + (size_t)p * NN * NN + (size_t)row * NN);
#pragma unroll
    for (int j = 0; j < 6; ++j) {
      uint4 q = rp[lane + j * 64];
      unsigned uu[4] = {q.x, q.y, q.z, q.w};
#pragma unroll
      for (int e = 0; e < 4; ++e) {
        f[j * 8 + e * 2] += __uint_as_float(uu[e] << 16);
        f[j * 8 + e * 2 + 1] += __uint_as_float(uu[e] & 0xffff0000u);
      }
    }
  }
}

static __device__ inline void load48_f32(const float* __restrict__ A, int row,
                                         int lane, float* f) {
  const float4* r0 = (const float4*)(A + (size_t)row * NN);
#pragma unroll
  for (int j = 0; j < 12; ++j) {
    float4 a = r0[lane + j * 64];
    f[j * 4 + 0] = a.x; f[j * 4 + 1] = a.y;
    f[j * 4 + 2] = a.z; f[j * 4 + 3] = a.w;
  }
}

// ---------------------------------------------------------------------------
// select top-64 of the wave's 64x48 values. Radix on bits [30..16] resolved
// TWO bits per step (counts are monotone c3<=c2<=c1, so "largest 2-bit
// pattern with count>=64" == two greedy single-bit steps) with butterfly
// shfl_xor reduces (all lanes end with the total -> no broadcast). Compact
// (idx*DD, val*scale) into out arrays (128 slots; LDS or global).
static __device__ void select_compact(const float* f, int lane, float descale,
                                      int bf, int* __restrict__ outCnt,
                                      int* __restrict__ outIdx,
                                      float* __restrict__ outVal) {
  unsigned bor = 0, band = 0xffffffffu;
#pragma unroll
  for (int r = 0; r < 48; ++r) {
    unsigned k = __float_as_uint(f[r]);
    bor |= k; band &= k;
  }
  for (int off = 32; off; off >>= 1) {
    bor |= (unsigned)__shfl_xor((int)bor, off, 64);
    band &= (unsigned)__shfl_xor((int)band, off, 64);
  }
  unsigned diff = bor ^ band;
  int hi = diff ? (31 - __clz(diff)) : 16;
  if (hi < 16) hi = 16;
  if (hi > 30) hi = 30;
  unsigned t = band & ~((2u << hi) - 1u);

  int b = hi;
  while (b >= 17) {
    unsigned base = 1u << (b - 1);
    unsigned cand1 = t | base;
    unsigned cand2 = t | (base << 1);
    unsigned cand3 = cand2 | base;
    int c1 = 0, c2 = 0, c3 = 0;
#pragma unroll
    for (int r = 0; r < 48; ++r) {
      unsigned k = __float_as_uint(f[r]);
      c1 += (k >= cand1) ? 1 : 0;
      c2 += (k >= cand2) ? 1 : 0;
      c3 += (k >= cand3) ? 1 : 0;
    }
    for (int off = 32; off; off >>= 1) {
      c1 += __shfl_xor(c1, off, 64);
      c2 += __shfl_xor(c2, off, 64);
      c3 += __shfl_xor(c3, off, 64);
    }
    if (c3 >= 64) t = cand3;
    else if (c2 >= 64) t = cand2;
    else if (c1 >= 64) t = cand1;
    b -= 2;
  }
  if (b == 16) {
    unsigned cand = t | (1u << 16);
    int c = 0;
#pragma unroll
    for (int r = 0; r < 48; ++r) c += (__float_as_uint(f[r]) >= cand) ? 1 : 0;
    for (int off = 32; off; off >>= 1) c += __shfl_xor(c, off, 64);
    if (c >= 64) t = cand;
  }

  int basec = 0;
#pragma unroll
  for (int r = 0; r < 48; ++r) {
    bool keep = __float_as_uint(f[r]) >= t;
    unsigned long long m = __ballot(keep);
    if (keep) {
      int pos = basec + __popcll(m & ((1ull << lane) - 1ull));
      if (pos < 128) {
        int col = bf ? ((r >> 3) * 512 + lane * 8 + (r & 7))
                     : ((r >> 2) * 256 + lane * 4 + (r & 3));
        outIdx[pos] = col << 7;  // pre-scaled by DD for gather addressing
        outVal[pos] = f[r] * descale;
      }
    }
    basec += __popcll(m);
  }
  if (lane == 0) *outCnt = basec < 128 ? basec : 128;
}

// ---------------------------------------------------------------------------
// prep: A -> fp8 PACKED (straight + transposed, x2^19) + fused y1/s1 matvec
// partials. grid 2304 (48x48 tiles of 64x64).
__global__ __launch_bounds__(256) void prep(
    const float* __restrict__ A, const float* __restrict__ vu,
    const float* __restrict__ vv, unsigned char* __restrict__ Af8,
    unsigned char* __restrict__ Atf8, float* __restrict__ y1,
    float* __restrict__ s1) {
  __shared__ float sh[64 * 65 + 512];
  const int bid = blockIdx.x;
  const int t = threadIdx.x;
  const int bx = (bid % 48) * 64, by = (bid / 48) * 64;
  const int rr = t >> 4;
  const int c4 = (t & 15) * 4;
  for (int it = 0; it < 4; ++it) {
    int r = rr + it * 16;
    float4 val = *(const float4*)(A + (size_t)(by + r) * NN + bx + c4);
    sh[r * 65 + c4] = val.x; sh[r * 65 + c4 + 1] = val.y;
    sh[r * 65 + c4 + 2] = val.z; sh[r * 65 + c4 + 3] = val.w;
  }
  __syncthreads();
  {
    int row = t >> 2, ch = t & 3;
    const float* sp = &sh[row * 65 + ch * 16];
    uint4 w;
    w.x = pk4_f8(sp[0] * SCALE_A, sp[1] * SCALE_A, sp[2] * SCALE_A,
                 sp[3] * SCALE_A);
    w.y = pk4_f8(sp[4] * SCALE_A, sp[5] * SCALE_A, sp[6] * SCALE_A,
                 sp[7] * SCALE_A);
    w.z = pk4_f8(sp[8] * SCALE_A, sp[9] * SCALE_A, sp[10] * SCALE_A,
                 sp[11] * SCALE_A);
    w.w = pk4_f8(sp[12] * SCALE_A, sp[13] * SCALE_A, sp[14] * SCALE_A,
                 sp[15] * SCALE_A);
    *(uint4*)(Af8 + (size_t)(bx >> 6) * KBLK + (size_t)(by + row) * 64 +
              ch * 16) = w;
  }
  {
    int c = t >> 2, ch = t & 3;
    float v[16];
#pragma unroll
    for (int e = 0; e < 16; ++e) v[e] = sh[(ch * 16 + e) * 65 + c];
    uint4 w;
    w.x = pk4_f8(v[0] * SCALE_A, v[1] * SCALE_A, v[2] * SCALE_A,
                 v[3] * SCALE_A);
    w.y = pk4_f8(v[4] * SCALE_A, v[5] * SCALE_A, v[6] * SCALE_A,
                 v[7] * SCALE_A);
    w.z = pk4_f8(v[8] * SCALE_A, v[9] * SCALE_A, v[10] * SCALE_A,
                 v[11] * SCALE_A);
    w.w = pk4_f8(v[12] * SCALE_A, v[13] * SCALE_A, v[14] * SCALE_A,
                 v[15] * SCALE_A);
    *(uint4*)(Atf8 + (size_t)(by >> 6) * KBLK + (size_t)(bx + c) * 64 +
              ch * 16) = w;
  }
  const int q = t >> 6;
  const int l = t & 63;
  float sy = 0.f, ss_ = 0.f;
  for (int i = 0; i < 16; ++i) {
    int c = q * 16 + i;
    sy += sh[l * 65 + c] * vv[bx + c];
    ss_ += vu[by + c] * sh[c * 65 + l];
  }
  float* red = sh + 64 * 65;
  red[q * 64 + l] = sy;
  red[256 + q * 64 + l] = ss_;
  __syncthreads();
  if (t < 64) {
    float v4 = red[t] + red[64 + t] + red[128 + t] + red[192 + t];
    atomAddF(&y1[by + t], v4);
  } else if (t < 128) {
    int cc = t - 64;
    float v4 = red[256 + cc] + red[256 + 64 + cc] + red[256 + 128 + cc] +
               red[256 + 192 + cc];
    atomAddF(&s1[bx + cc], v4);
  }
}

// ---------------------------------------------------------------------------
// LDS-free fp8 GEMM via MX-scaled 32x32x64 MFMA at unit scales.
// v5: prefetch DISTANCE-2 register pipeline (3 named buffer sets, 3x-unrolled
// rotation; every set has two MFMA clusters between load-issue and use ->
// ~270 cycles of latency cover at 2 waves/SIMD, matching L2 latency).
// nIter is 24 or 48 (both %3==0) so the rotation has no MFMA tail; prefetch
// indices are clamped (duplicate loads are harmless, never consumed).
static __device__ inline i32x8 ldfrag(const unsigned char* p) {
  i32x4 lo = *(const i32x4*)p;
  i32x4 hi = *(const i32x4*)(p + 16);
  return (i32x8){lo.x, lo.y, lo.z, lo.w, hi.x, hi.y, hi.z, hi.w};
}

#define MFMA4(A0, A1, B0, B1)                                          \
  acc[0][0] = __builtin_amdgcn_mfma_scale_f32_32x32x64_f8f6f4(         \
      A0, B0, acc[0][0], 0, 0, 0, 127, 0, 127);                        \
  acc[0][1] = __builtin_amdgcn_mfma_scale_f32_32x32x64_f8f6f4(         \
      A0, B1, acc[0][1], 0, 0, 0, 127, 0, 127);                        \
  acc[1][0] = __builtin_amdgcn_mfma_scale_f32_32x32x64_f8f6f4(         \
      A1, B0, acc[1][0], 0, 0, 0, 127, 0, 127);                        \
  acc[1][1] = __builtin_amdgcn_mfma_scale_f32_32x32x64_f8f6f4(         \
      A1, B1, acc[1][1], 0, 0, 0, 127, 0, 127);

__global__ __launch_bounds__(256) void gemm_f8(
    const unsigned char* __restrict__ Ag,
    const unsigned char* __restrict__ Btg,
    unsigned short* __restrict__ Cg, int kLen) {
  const int tid = threadIdx.x;
  const int wave = tid >> 6;
  const int lane = tid & 63;
  const int rowBase = blockIdx.y * 128;
  const int colBase = blockIdx.x * 128;
  const int wr = wave >> 1, wc = wave & 1;
  const int r32 = lane & 31, hh = lane >> 5;
  const int kStart = blockIdx.z * kLen;
  unsigned short* Cout = Cg + (size_t)blockIdx.z * NN * NN;

  f32x16 acc[2][2];
  for (int i = 0; i < 2; ++i)
    for (int j = 0; j < 2; ++j)
      for (int e = 0; e < 16; ++e) acc[i][j][e] = 0.f;

  const unsigned char* aB0 = Ag + (size_t)(kStart >> 6) * KBLK +
                             (size_t)(rowBase + (wr * 2) * 32 + r32) * 64 +
                             hh * 32;
  const unsigned char* aB1 = aB0 + 32 * 64;
  const unsigned char* bB0 = Btg + (size_t)(kStart >> 6) * KBLK +
                             (size_t)(colBase + (wc * 2) * 32 + r32) * 64 +
                             hh * 32;
  const unsigned char* bB1 = bB0 + 32 * 64;

  const int nIter = kLen >> 6;
  i32x8 a0s0, a1s0, b0s0, b1s0;
  i32x8 a0s1, a1s1, b0s1, b1s1;
  i32x8 a0s2, a1s2, b0s2, b1s2;

#define LDSET(A0, A1, B0, B1, i)                        \
  {                                                     \
    int jj = (i) < nIter ? (i) : nIter - 1;             \
    size_t o = (size_t)jj * KBLK;                       \
    A0 = ldfrag(aB0 + o);                               \
    A1 = ldfrag(aB1 + o);                               \
    B0 = ldfrag(bB0 + o);                               \
    B1 = ldfrag(bB1 + o);                               \
  }

  LDSET(a0s0, a1s0, b0s0, b1s0, 0);
  LDSET(a0s1, a1s1, b0s1, b1s1, 1);
  // main rotation: nIter % 3 == 0 guaranteed (kLen = 3072 or 1536)
  for (int it = 0; it < nIter; it += 3) {
    LDSET(a0s2, a1s2, b0s2, b1s2, it + 2);
    MFMA4(a0s0, a1s0, b0s0, b1s0);
    LDSET(a0s0, a1s0, b0s0, b1s0, it + 3);
    MFMA4(a0s1, a1s1, b0s1, b1s1);
    LDSET(a0s1, a1s1, b0s1, b1s1, it + 4);
    MFMA4(a0s2, a1s2, b0s2, b1s2);
  }
#undef LDSET

  // C/D 32x32 layout: col = lane&31, row = (reg&3) + 8*(reg>>2) + 4*(lane>>5)
  for (int i = 0; i < 2; ++i) {
    int rb = rowBase + wr * 64 + i * 32 + 4 * hh;
    for (int j = 0; j < 2; ++j) {
      int cc = colBase + wc * 64 + j * 32 + r32;
      for (int reg = 0; reg < 16; ++reg) {
        int rr = rb + (reg & 3) + 8 * (reg >> 2);
        Cout[(size_t)rr * NN + cc] = bf16bits(acc[i][j][reg]);
      }
    }
  }
}

// ---------------------------------------------------------------------------
// post1: [0,768)     topk(A2 bf16 partial-sum) + packed fp8 cast -> A2f8
//        [768,1536)  tvec = A.y1 (one wave per row)
//        [1536,1920) concat uemb/iemb -> allE (aliases dead Af8)
__global__ __launch_bounds__(256) void post1(
    const unsigned short* __restrict__ C, int parts,
    const float* __restrict__ A, const float* __restrict__ y1,
    unsigned char* __restrict__ A2f8, int* __restrict__ cnts1,
    int* __restrict__ tIdx1, float* __restrict__ tVal1,
    float* __restrict__ tvec, const float* __restrict__ uemb,
    const float* __restrict__ iemb, float* __restrict__ allE) {
  const int bid = blockIdx.x;
  const int t = threadIdx.x;
  if (bid < 768) {
    int row = bid * 4 + (t >> 6);
    int lane = t & 63;
    float f[48];
    load48_bf(C, parts, row, lane, f);
    // fused packed fp8 cast: f[j*8+e] = col k0+e, k0=(j*64+lane)*8
#pragma unroll
    for (int j = 0; j < 6; ++j) {
      uint2 w;
      w.x = pk4_f8(f[j * 8 + 0] * F8SCALE2, f[j * 8 + 1] * F8SCALE2,
                   f[j * 8 + 2] * F8SCALE2, f[j * 8 + 3] * F8SCALE2);
      w.y = pk4_f8(f[j * 8 + 4] * F8SCALE2, f[j * 8 + 5] * F8SCALE2,
                   f[j * 8 + 6] * F8SCALE2, f[j * 8 + 7] * F8SCALE2);
      size_t addr = (size_t)(j * 8 + (lane >> 3)) * KBLK +
                    (size_t)row * 64 + (lane & 7) * 8;
      *(uint2*)(A2f8 + addr) = w;
    }
    select_compact(f, lane, DESCALE38, 1, &cnts1[row],
                   tIdx1 + (size_t)row * 128, tVal1 + (size_t)row * 128);
  } else if (bid < 1536) {
    int row = (bid - 768) * 4 + (t >> 6);
    int lane = t & 63;
    const float4* rp = (const float4*)(A + (size_t)row * NN);
    const float4* yp = (const float4*)y1;
    float s = 0.f;
#pragma unroll
    for (int j = 0; j < 12; ++j) {
      float4 a = rp[lane + j * 64];
      float4 y = yp[lane + j * 64];
      s += a.x * y.x + a.y * y.y + a.z * y.z + a.w * y.w;
    }
    for (int off = 32; off; off >>= 1) s += __shfl_down(s, off, 64);
    if (lane == 0) tvec[row] = s;
  } else {
    // concat embeddings into allE[NN][DD]; 384 blocks x 256 thr x float4
    int idx = (bid - 1536) * 256 + t;
    int e = idx * 4;
    float4 v = (e < NU * DD) ? *(const float4*)(uemb + e)
                             : *(const float4*)(iemb + (e - NU * DD));
    *(float4*)(allE + e) = v;
  }
}

// ---------------------------------------------------------------------------
// post2: single block -> w0..w3
__global__ __launch_bounds__(256) void post2(
    const float* __restrict__ vu, const float* __restrict__ vv,
    const float* __restrict__ y1, const float* __restrict__ s1,
    const float* __restrict__ tvec, float* __restrict__ wacc) {
  __shared__ float red4[4];
  const int t = threadIdx.x;
  float w0 = row_dot_f32(vu, vv, red4);  __syncthreads();
  float w1 = row_dot_f32(vu, y1, red4);  __syncthreads();
  float w2 = row_dot_f32(s1, y1, red4);  __syncthreads();
  float w3 = row_dot_f32(s1, tvec, red4);
  if (t == 0) { wacc[0] = w0; wacc[1] = w1; wacc[2] = w2; wacc[3] = w3; }
}

// ---------------------------------------------------------------------------
// sel02: phase-homogeneous select kernel (one select per wave, dense waves).
//   bid even: layer-2 lists from C (A3 bf16 partials) -> global
//   bid odd:  layer-0 lists from A (fp32)             -> global
// (interleaved so heavy/light blocks co-schedule; avoids the tail imbalance
// of a split-range grid). Lists land in the dead Atf8 buffer.
__global__ __launch_bounds__(256) void sel02(
    const unsigned short* __restrict__ C, int parts,
    const float* __restrict__ A, int* __restrict__ cnt0,
    int* __restrict__ idx0, float* __restrict__ val0,
    int* __restrict__ cnt2, int* __restrict__ idx2,
    float* __restrict__ val2) {
  const int bid = blockIdx.x;
  const int t = threadIdx.x;
  const int w = t >> 6, lane = t & 63;
  const int row = (bid >> 1) * 4 + w;
  float f[48];
  if ((bid & 1) == 0) {
    load48_bf(C, parts, row, lane, f);
    select_compact(f, lane, DESCALE38, 1, &cnt2[row],
                   idx2 + (size_t)row * 128, val2 + (size_t)row * 128);
  } else {
    load48_f32(A, row, lane, f);
    select_compact(f, lane, 1.0f, 0, &cnt0[row],
                   idx0 + (size_t)row * 128, val0 + (size_t)row * 128);
  }
}

// ---------------------------------------------------------------------------
// gather_light: pure gather, one wave per row (768 blocks x 256 thr).
// All three layer lists concatenated into one LDS run with the attention
// weights folded into the values at staging; float2 gather (64 lanes cover
// the 128 dims), 8 independent loads in flight, no __syncthreads.
__global__ __launch_bounds__(256) void gather_light(
    const float* __restrict__ allE, const float* __restrict__ uemb0,
    const float* __restrict__ iemb0, const float* __restrict__ wacc,
    const int* __restrict__ cnt0, const int* __restrict__ idx0,
    const float* __restrict__ val0, const int* __restrict__ cnts1,
    const int* __restrict__ tIdx1, const float* __restrict__ tVal1,
    const int* __restrict__ cnt2, const int* __restrict__ idx2,
    const float* __restrict__ val2, float* __restrict__ lightOut) {
  __shared__ int li[4][384];
  __shared__ float lv[4][384];
  const int t = threadIdx.x;
  const int w = t >> 6, lane = t & 63;
  const int row = blockIdx.x * 4 + w;

  float w0 = wacc[0], w1 = wacc[1], w2 = wacc[2], w3 = wacc[3];
  float ss = w0 + w1 + w2 + w3;
  w0 /= ss; w1 /= ss; w2 /= ss; w3 /= ss;
  float m = fmaxf(fmaxf(w0, w1), fmaxf(w2, w3));
  float ex0 = expf(w0 - m), ex1 = expf(w1 - m), ex2 = expf(w2 - m),
        ex3 = expf(w3 - m);
  float se = ex0 + ex1 + ex2 + ex3;
  float aw0 = ex0 / se, aw1 = ex1 / se, aw2 = ex2 / se, aw3 = ex3 / se;
  float aw4 = GAMMA_F * (aw1 + aw2 + aw3);

  const int c0 = cnt0[row], c1 = cnts1[row], c2 = cnt2[row];
  const int p0 = (c0 + 7) & ~7, p1 = (c1 + 7) & ~7, p2 = (c2 + 7) & ~7;
  int* Li = li[w];
  float* Lv = lv[w];
  const size_t rb = (size_t)row * 128;
  for (int k = lane; k < p0; k += 64) {
    bool in = k < c0;
    Li[k] = in ? idx0[rb + k] : 0;
    Lv[k] = in ? aw1 * val0[rb + k] : 0.f;
  }
  for (int k = lane; k < p1; k += 64) {
    bool in = k < c1;
    Li[p0 + k] = in ? tIdx1[rb + k] : 0;
    Lv[p0 + k] = in ? aw2 * tVal1[rb + k] : 0.f;
  }
  for (int k = lane; k < p2; k += 64) {
    bool in = k < c2;
    Li[p0 + p1 + k] = in ? idx2[rb + k] : 0;
    Lv[p0 + p1 + k] = in ? aw3 * val2[rb + k] : 0.f;
  }
  // same-wave produce->consume through LDS: compiler orders via lgkmcnt.

  const int ct = p0 + p1 + p2;
  const float2* E2 = (const float2*)allE;
  float ax = 0.f, ay = 0.f, bx_ = 0.f, by_ = 0.f;
  for (int k = 0; k < ct; k += 8) {
    int i0 = Li[k + 0], i1 = Li[k + 1], i2 = Li[k + 2], i3 = Li[k + 3];
    int i4 = Li[k + 4], i5 = Li[k + 5], i6 = Li[k + 6], i7 = Li[k + 7];
    float v0 = Lv[k + 0], v1 = Lv[k + 1], v2 = Lv[k + 2], v3 = Lv[k + 3];
    float v4 = Lv[k + 4], v5 = Lv[k + 5], v6 = Lv[k + 6], v7 = Lv[k + 7];
    float2 g0 = E2[(i0 >> 1) + lane];
    float2 g1 = E2[(i1 >> 1) + lane];
    float2 g2 = E2[(i2 >> 1) + lane];
    float2 g3 = E2[(i3 >> 1) + lane];
    float2 g4 = E2[(i4 >> 1) + lane];
    float2 g5 = E2[(i5 >> 1) + lane];
    float2 g6 = E2[(i6 >> 1) + lane];
    float2 g7 = E2[(i7 >> 1) + lane];
    ax += v0 * g0.x; ay += v0 * g0.y;
    bx_ += v1 * g1.x; by_ += v1 * g1.y;
    ax += v2 * g2.x; ay += v2 * g2.y;
    bx_ += v3 * g3.x; by_ += v3 * g3.y;
    ax += v4 * g4.x; ay += v4 * g4.y;
    bx_ += v5 * g5.x; by_ += v5 * g5.y;
    ax += v6 * g6.x; ay += v6 * g6.y;
    bx_ += v7 * g7.x; by_ += v7 * g7.y;
  }
  float2 sE = E2[((size_t)row << 6) + lane];
  float2 e0 = (row < NU)
                  ? ((const float2*)uemb0)[(size_t)row * 64 + lane]
                  : ((const float2*)iemb0)[(size_t)(row - NU) * 64 + lane];
  float ox = (ax + bx_) + aw0 * sE.x + aw4 * e0.x;
  float oy = (ay + by_) + aw0 * sE.y + aw4 * e0.y;
  float2 o; o.x = ox; o.y = oy;
  ((float2*)lightOut)[(size_t)row * 64 + lane] = o;
}

__global__ __launch_bounds__(256) void out_dot(const int* __restrict__ users,
                                               const int* __restrict__ items,
                                               const float* __restrict__ lightOut,
                                               float* __restrict__ out) {
  int b = blockIdx.x * 4 + (threadIdx.x >> 6);
  int lane = threadIdx.x & 63;
  const float* up = lightOut + (size_t)users[b] * DD;
  const float* ip = lightOut + (size_t)(NU + items[b]) * DD;
  float s = up[lane] * ip[lane] + up[lane + 64] * ip[lane + 64];
  for (int off = 32; off; off >>= 1) s += __shfl_down(s, off, 64);
  if (lane == 0) out[b] = s;
}

// ---------------------------------------------------------------------------
extern "C" void kernel_launch(void* const* d_in, const int* in_sizes, int n_in,
                              void* d_out, int out_size, void* d_ws,
                              size_t ws_size, hipStream_t stream) {
  const int* users = (const int*)d_in[0];
  const int* items = (const int*)d_in[1];
  const float* A = (const float*)d_in[2];
  const float* uemb = (const float*)d_in[3];
  const float* iemb = (const float*)d_in[4];
  const float* uemb0 = (const float*)d_in[5];
  const float* iemb0 = (const float*)d_in[6];
  const float* vu = (const float*)d_in[7];
  const float* vv = (const float*)d_in[8];
  float* out = (float*)d_out;

  char* ws = (char*)d_ws;
  size_t off = 0;
  auto alloc = [&](size_t bytes) -> void* {
    void* p = ws + off;
    off += (bytes + 255) & ~(size_t)255;
    return p;
  };
  unsigned char* Af8 = (unsigned char*)alloc((size_t)NN * NN);
  unsigned char* Atf8 = (unsigned char*)alloc((size_t)NN * NN);
  unsigned char* A2f8 = (unsigned char*)alloc((size_t)NN * NN);
  float* y1 = (float*)alloc((size_t)NN * 4);   // contiguous with s1
  float* s1 = (float*)alloc((size_t)NN * 4);
  float* tvec = (float*)alloc((size_t)NN * 4);
  float* wacc = (float*)alloc(256);
  int* cnts1 = (int*)alloc((size_t)NN * 4);
  int* tIdx1 = (int*)alloc((size_t)NN * 128 * 4);
  float* tVal1 = (float*)alloc((size_t)NN * 128 * 4);
  float* lightOut = (float*)alloc((size_t)NN * DD * 4);
  int* cnt0 = (int*)alloc((size_t)NN * 4);
  int* cnt2 = (int*)alloc((size_t)NN * 4);

  // allE (NN*DD fp32 = 1.5 MB) aliases Af8 (9.4 MB): Af8 is dead after
  // gemm#1 (step 3); post1 (step 4) writes allE; gather (step 8) reads.
  float* allE = (float*)Af8;
  // layer-0/2 lists (4 x 1.5 MB) alias Atf8 (9.4 MB): Atf8 is dead after
  // gemm#2 (step 5); sel02 (step 6) writes, gather (step 8) reads.
  const size_t LSTB = (size_t)NN * 128 * 4;
  int* idx0 = (int*)(Atf8);
  float* val0 = (float*)(Atf8 + LSTB);
  int* idx2 = (int*)(Atf8 + 2 * LSTB);
  float* val2 = (float*)(Atf8 + 3 * LSTB);

  const size_t cBytes = (size_t)NN * NN * 2;  // bf16 partials
  int kParts = (ws_size >= off + 2 * cBytes + 512) ? 2 : 1;
  unsigned short* C = (unsigned short*)alloc((size_t)kParts * cBytes);
  const int kLen = NN / kParts;

  // 1) zero y1/s1 (contiguous 2*NN floats)
  hipMemsetAsync(y1, 0, (size_t)2 * NN * 4, stream);
  // 2) prep: A -> packed fp8 (straight+transposed) + y1/s1 partials
  prep<<<2304, 256, 0, stream>>>(A, vu, vv, Af8, Atf8, y1, s1);
  // 3) A2 = A*A (depth-2 register-pipelined MX fp8 MFMA, bf16 partials x2)
  gemm_f8<<<dim3(24, 24, kParts), 256, 0, stream>>>(Af8, Atf8, C, kLen);
  // 4) post1: topk(A2)+packed fp8 cast | tvec = A.y1 | emb concat -> allE
  post1<<<1920, 256, 0, stream>>>(C, kParts, A, y1, A2f8, cnts1, tIdx1,
                                  tVal1, tvec, uemb, iemb, allE);
  // 5) A3 = A2*A (overwrite partials)
  gemm_f8<<<dim3(24, 24, kParts), 256, 0, stream>>>(A2f8, Atf8, C, kLen);
  // 6) sel02: layer-0 (A) and layer-2 (A3) top-64 lists -> global (in Atf8)
  sel02<<<1536, 256, 0, stream>>>(C, kParts, A, cnt0, idx0, val0, cnt2, idx2,
                                  val2);
  // 7) post2: w0..w3 (single block)
  post2<<<1, 256, 0, stream>>>(vu, vv, y1, s1, tvec, wacc);
  // 8) gather_light: pure float2 gather, one wave per row
  gather_light<<<768, 256, 0, stream>>>(allE, uemb0, iemb0, wacc, cnt0, idx0,
                                        val0, cnts1, tIdx1, tVal1, cnt2, idx2,
                                        val2, lightOut);
  // 9) gather dots
  out_dot<<<BB / 4, 256, 0, stream>>>(users, items, lightOut, out);
}

// Round 5
// 315.930 us; speedup vs baseline: 1.0047x; 1.0047x over previous
//
#include <hip/hip_runtime.h>
#include <hip/hip_fp8.h>
#include <math.h>

#define NN 3072
#define NU 1024
#define NI 2048
#define DD 128
#define BB 8192
#define GAMMA_F 0.2f

#define SCALE_A 524288.0f                // 2^19
#define F8SCALE2 1.9073486328125e-06f    // 2^-19  (C*2^38 -> A2*2^19 for fp8)
#define DESCALE38 3.637978807091713e-12f // 2^-38  (C -> true A^k values)

// packed fp8 layout: [k/64][row][k%64]; one k-block = NN rows x 64 B
#define KBLK ((size_t)NN * 64)

typedef __attribute__((ext_vector_type(4))) float f32x4;
typedef __attribute__((ext_vector_type(16))) float f32x16;
typedef __attribute__((ext_vector_type(4))) int i32x4;
typedef __attribute__((ext_vector_type(8))) int i32x8;

static __device__ inline unsigned short bf16bits(float x) {
  union { unsigned u; float f; } cv;
  cv.f = x;
  unsigned r = cv.u + 0x7fff + ((cv.u >> 16) & 1);  // RNE
  return (unsigned short)(r >> 16);
}

// pack 4 floats -> 4 fp8 e4m3 (OCP) bytes
static __device__ inline unsigned pk4_f8(float a, float b, float c, float d) {
#if defined(__has_builtin)
#if __has_builtin(__builtin_amdgcn_cvt_pk_fp8_f32)
  int p = __builtin_amdgcn_cvt_pk_fp8_f32(a, b, 0, false);
  p = __builtin_amdgcn_cvt_pk_fp8_f32(c, d, p, true);
  return (unsigned)p;
#else
  return (unsigned)__hip_fp8_e4m3(a).__x | ((unsigned)__hip_fp8_e4m3(b).__x << 8) |
         ((unsigned)__hip_fp8_e4m3(c).__x << 16) |
         ((unsigned)__hip_fp8_e4m3(d).__x << 24);
#endif
#else
  return (unsigned)__hip_fp8_e4m3(a).__x | ((unsigned)__hip_fp8_e4m3(b).__x << 8) |
         ((unsigned)__hip_fp8_e4m3(c).__x << 16) |
         ((unsigned)__hip_fp8_e4m3(d).__x << 24);
#endif
}

static __device__ inline void atomAddF(float* p, float v) {
#if defined(__has_builtin)
#if __has_builtin(__builtin_amdgcn_global_atomic_fadd_f32)
  __builtin_amdgcn_global_atomic_fadd_f32(
      (__attribute__((address_space(1))) float*)p, v);
#else
  unsafeAtomicAdd(p, v);
#endif
#else
  unsafeAtomicAdd(p, v);
#endif
}

static __device__ inline float block_sum(float s, float* red4) {
  int tid = threadIdx.x;
  for (int off = 32; off; off >>= 1) s += __shfl_down(s, off, 64);
  if ((tid & 63) == 0) red4[tid >> 6] = s;
  __syncthreads();
  return red4[0] + red4[1] + red4[2] + red4[3];
}

static __device__ inline float row_dot_f32(const float* __restrict__ a,
                                           const float* __restrict__ b,
                                           float* red4) {
  const float4* ap = (const float4*)a;
  const float4* bp = (const float4*)b;
  float s = 0.f;
  for (int j = threadIdx.x; j < NN / 4; j += 256) {
    float4 x = ap[j], y = bp[j];
    s += x.x * y.x + x.y * y.y + x.z * y.z + x.w * y.w;
  }
  return block_sum(s, red4);
}

// ---------------------------------------------------------------------------
// topk loaders: fill f[48] with this row's values (one wave, 48 vals/lane).
static __device__ inline void load48_bf(const unsigned short* __restrict__ b0,
                                        int parts, int row, int lane,
                                        float* f) {
  const uint4* r0 = (const uint4*)(b0 + (size_t)row * NN);
#pragma unroll
  for (int j = 0; j < 6; ++j) {
    uint4 q = r0[lane + j * 64];
    unsigned uu[4] = {q.x, q.y, q.z, q.w};
#pragma unroll
    for (int e = 0; e < 4; ++e) {
      f[j * 8 + e * 2] = __uint_as_float(uu[e] << 16);
      f[j * 8 + e * 2 + 1] = __uint_as_float(uu[e] & 0xffff0000u);
    }
  }
  for (int p = 1; p < parts; ++p) {
    const uint4* rp = (const uint4*)(b0 + (size_t)p * NN * NN + (size_t)row * NN);
#pragma unroll
    for (int j = 0; j < 6; ++j) {
      uint4 q = rp[lane + j * 64];
      unsigned uu[4] = {q.x, q.y, q.z, q.w};
#pragma unroll
      for (int e = 0; e < 4; ++e) {
        f[j * 8 + e * 2] += __uint_as_float(uu[e] << 16);
        f[j * 8 + e * 2 + 1] += __uint_as_float(uu[e] & 0xffff0000u);
      }
    }
  }
}

static __device__ inline void load48_f32(const float* __restrict__ A, int row,
                                         int lane, float* f) {
  const float4* r0 = (const float4*)(A + (size_t)row * NN);
#pragma unroll
  for (int j = 0; j < 12; ++j) {
    float4 a = r0[lane + j * 64];
    f[j * 4 + 0] = a.x; f[j * 4 + 1] = a.y;
    f[j * 4 + 2] = a.z; f[j * 4 + 3] = a.w;
  }
}

// ---------------------------------------------------------------------------
// select top-64 of the wave's 64x48 values. Radix on bits [30..16] resolved
// TWO bits per step (counts are monotone c3<=c2<=c1, so "largest 2-bit
// pattern with count>=64" == two greedy single-bit steps) with butterfly
// shfl_xor reduces (all lanes end with the total -> no broadcast). Compact
// (idx*DD, val*scale) into out arrays (128 slots; LDS or global).
static __device__ void select_compact(const float* f, int lane, float descale,
                                      int bf, int* __restrict__ outCnt,
                                      int* __restrict__ outIdx,
                                      float* __restrict__ outVal) {
  unsigned bor = 0, band = 0xffffffffu;
#pragma unroll
  for (int r = 0; r < 48; ++r) {
    unsigned k = __float_as_uint(f[r]);
    bor |= k; band &= k;
  }
  for (int off = 32; off; off >>= 1) {
    bor |= (unsigned)__shfl_xor((int)bor, off, 64);
    band &= (unsigned)__shfl_xor((int)band, off, 64);
  }
  unsigned diff = bor ^ band;
  int hi = diff ? (31 - __clz(diff)) : 16;
  if (hi < 16) hi = 16;
  if (hi > 30) hi = 30;
  unsigned t = band & ~((2u << hi) - 1u);

  int b = hi;
  while (b >= 17) {
    unsigned base = 1u << (b - 1);
    unsigned cand1 = t | base;
    unsigned cand2 = t | (base << 1);
    unsigned cand3 = cand2 | base;
    int c1 = 0, c2 = 0, c3 = 0;
#pragma unroll
    for (int r = 0; r < 48; ++r) {
      unsigned k = __float_as_uint(f[r]);
      c1 += (k >= cand1) ? 1 : 0;
      c2 += (k >= cand2) ? 1 : 0;
      c3 += (k >= cand3) ? 1 : 0;
    }
    for (int off = 32; off; off >>= 1) {
      c1 += __shfl_xor(c1, off, 64);
      c2 += __shfl_xor(c2, off, 64);
      c3 += __shfl_xor(c3, off, 64);
    }
    if (c3 >= 64) t = cand3;
    else if (c2 >= 64) t = cand2;
    else if (c1 >= 64) t = cand1;
    b -= 2;
  }
  if (b == 16) {
    unsigned cand = t | (1u << 16);
    int c = 0;
#pragma unroll
    for (int r = 0; r < 48; ++r) c += (__float_as_uint(f[r]) >= cand) ? 1 : 0;
    for (int off = 32; off; off >>= 1) c += __shfl_xor(c, off, 64);
    if (c >= 64) t = cand;
  }

  int basec = 0;
#pragma unroll
  for (int r = 0; r < 48; ++r) {
    bool keep = __float_as_uint(f[r]) >= t;
    unsigned long long m = __ballot(keep);
    if (keep) {
      int pos = basec + __popcll(m & ((1ull << lane) - 1ull));
      if (pos < 128) {
        int col = bf ? ((r >> 3) * 512 + lane * 8 + (r & 7))
                     : ((r >> 2) * 256 + lane * 4 + (r & 3));
        outIdx[pos] = col << 7;  // pre-scaled by DD for gather addressing
        outVal[pos] = f[r] * descale;
      }
    }
    basec += __popcll(m);
  }
  if (lane == 0) *outCnt = basec < 128 ? basec : 128;
}

// ---------------------------------------------------------------------------
// prep: A -> fp8 PACKED (straight + transposed, x2^19) + fused y1/s1 matvec
// partials. grid 2304 (48x48 tiles of 64x64).
__global__ __launch_bounds__(256) void prep(
    const float* __restrict__ A, const float* __restrict__ vu,
    const float* __restrict__ vv, unsigned char* __restrict__ Af8,
    unsigned char* __restrict__ Atf8, float* __restrict__ y1,
    float* __restrict__ s1) {
  __shared__ float sh[64 * 65 + 512];
  const int bid = blockIdx.x;
  const int t = threadIdx.x;
  const int bx = (bid % 48) * 64, by = (bid / 48) * 64;
  const int rr = t >> 4;
  const int c4 = (t & 15) * 4;
  for (int it = 0; it < 4; ++it) {
    int r = rr + it * 16;
    float4 val = *(const float4*)(A + (size_t)(by + r) * NN + bx + c4);
    sh[r * 65 + c4] = val.x; sh[r * 65 + c4 + 1] = val.y;
    sh[r * 65 + c4 + 2] = val.z; sh[r * 65 + c4 + 3] = val.w;
  }
  __syncthreads();
  {
    int row = t >> 2, ch = t & 3;
    const float* sp = &sh[row * 65 + ch * 16];
    uint4 w;
    w.x = pk4_f8(sp[0] * SCALE_A, sp[1] * SCALE_A, sp[2] * SCALE_A,
                 sp[3] * SCALE_A);
    w.y = pk4_f8(sp[4] * SCALE_A, sp[5] * SCALE_A, sp[6] * SCALE_A,
                 sp[7] * SCALE_A);
    w.z = pk4_f8(sp[8] * SCALE_A, sp[9] * SCALE_A, sp[10] * SCALE_A,
                 sp[11] * SCALE_A);
    w.w = pk4_f8(sp[12] * SCALE_A, sp[13] * SCALE_A, sp[14] * SCALE_A,
                 sp[15] * SCALE_A);
    *(uint4*)(Af8 + (size_t)(bx >> 6) * KBLK + (size_t)(by + row) * 64 +
              ch * 16) = w;
  }
  {
    int c = t >> 2, ch = t & 3;
    float v[16];
#pragma unroll
    for (int e = 0; e < 16; ++e) v[e] = sh[(ch * 16 + e) * 65 + c];
    uint4 w;
    w.x = pk4_f8(v[0] * SCALE_A, v[1] * SCALE_A, v[2] * SCALE_A,
                 v[3] * SCALE_A);
    w.y = pk4_f8(v[4] * SCALE_A, v[5] * SCALE_A, v[6] * SCALE_A,
                 v[7] * SCALE_A);
    w.z = pk4_f8(v[8] * SCALE_A, v[9] * SCALE_A, v[10] * SCALE_A,
                 v[11] * SCALE_A);
    w.w = pk4_f8(v[12] * SCALE_A, v[13] * SCALE_A, v[14] * SCALE_A,
                 v[15] * SCALE_A);
    *(uint4*)(Atf8 + (size_t)(by >> 6) * KBLK + (size_t)(bx + c) * 64 +
              ch * 16) = w;
  }
  const int q = t >> 6;
  const int l = t & 63;
  float sy = 0.f, ss_ = 0.f;
  for (int i = 0; i < 16; ++i) {
    int c = q * 16 + i;
    sy += sh[l * 65 + c] * vv[bx + c];
    ss_ += vu[by + c] * sh[c * 65 + l];
  }
  float* red = sh + 64 * 65;
  red[q * 64 + l] = sy;
  red[256 + q * 64 + l] = ss_;
  __syncthreads();
  if (t < 64) {
    float v4 = red[t] + red[64 + t] + red[128 + t] + red[192 + t];
    atomAddF(&y1[by + t], v4);
  } else if (t < 128) {
    int cc = t - 64;
    float v4 = red[256 + cc] + red[256 + 64 + cc] + red[256 + 128 + cc] +
               red[256 + 192 + cc];
    atomAddF(&s1[bx + cc], v4);
  }
}

// ---------------------------------------------------------------------------
// LDS-free fp8 GEMM via MX-scaled 32x32x64 MFMA at unit scales.
// v6: depth-2 register pipeline PINNED with sched_barrier(0) (v5's rotation
// was legal to re-sink; at VGPR=84 the allocator collapsed it to depth<=1 —
// the fences force all 3 load-sets live) + bijective XCD-chunked block
// swizzle (each XCD gets 6 contiguous output rows -> A/B K-slices L2-fit,
// turning ~900cy L3/HBM misses into ~200cy L2 hits that depth-2 covers).
static __device__ inline i32x8 ldfrag(const unsigned char* p) {
  i32x4 lo = *(const i32x4*)p;
  i32x4 hi = *(const i32x4*)(p + 16);
  return (i32x8){lo.x, lo.y, lo.z, lo.w, hi.x, hi.y, hi.z, hi.w};
}

#define MFMA4(A0, A1, B0, B1)                                          \
  acc[0][0] = __builtin_amdgcn_mfma_scale_f32_32x32x64_f8f6f4(         \
      A0, B0, acc[0][0], 0, 0, 0, 127, 0, 127);                        \
  acc[0][1] = __builtin_amdgcn_mfma_scale_f32_32x32x64_f8f6f4(         \
      A0, B1, acc[0][1], 0, 0, 0, 127, 0, 127);                        \
  acc[1][0] = __builtin_amdgcn_mfma_scale_f32_32x32x64_f8f6f4(         \
      A1, B0, acc[1][0], 0, 0, 0, 127, 0, 127);                        \
  acc[1][1] = __builtin_amdgcn_mfma_scale_f32_32x32x64_f8f6f4(         \
      A1, B1, acc[1][1], 0, 0, 0, 127, 0, 127);

__global__ __launch_bounds__(256) void gemm_f8(
    const unsigned char* __restrict__ Ag,
    const unsigned char* __restrict__ Btg,
    unsigned short* __restrict__ Cg, int kLen) {
  // bijective XCD chunk swizzle: nwg = 576*kParts, nwg%8==0 always.
  const int nwg = gridDim.x;
  const int chunk = nwg >> 3;
  const int bid = blockIdx.x;
  const int wgid = (bid & 7) * chunk + (bid >> 3);
  const int z = wgid / 576;
  const int rr_ = wgid - z * 576;
  const int byi = rr_ / 24;
  const int bxi = rr_ - byi * 24;

  const int tid = threadIdx.x;
  const int wave = tid >> 6;
  const int lane = tid & 63;
  const int rowBase = byi * 128;
  const int colBase = bxi * 128;
  const int wr = wave >> 1, wc = wave & 1;
  const int r32 = lane & 31, hh = lane >> 5;
  const int kStart = z * kLen;
  unsigned short* Cout = Cg + (size_t)z * NN * NN;

  f32x16 acc[2][2];
  for (int i = 0; i < 2; ++i)
    for (int j = 0; j < 2; ++j)
      for (int e = 0; e < 16; ++e) acc[i][j][e] = 0.f;

  const unsigned char* aB0 = Ag + (size_t)(kStart >> 6) * KBLK +
                             (size_t)(rowBase + (wr * 2) * 32 + r32) * 64 +
                             hh * 32;
  const unsigned char* aB1 = aB0 + 32 * 64;
  const unsigned char* bB0 = Btg + (size_t)(kStart >> 6) * KBLK +
                             (size_t)(colBase + (wc * 2) * 32 + r32) * 64 +
                             hh * 32;
  const unsigned char* bB1 = bB0 + 32 * 64;

  const int nIter = kLen >> 6;
  i32x8 a0s0, a1s0, b0s0, b1s0;
  i32x8 a0s1, a1s1, b0s1, b1s1;
  i32x8 a0s2, a1s2, b0s2, b1s2;

#define LDSET(A0, A1, B0, B1, i)                        \
  {                                                     \
    int jj = (i) < nIter ? (i) : nIter - 1;             \
    size_t o = (size_t)jj * KBLK;                       \
    A0 = ldfrag(aB0 + o);                               \
    A1 = ldfrag(aB1 + o);                               \
    B0 = ldfrag(bB0 + o);                               \
    B1 = ldfrag(bB1 + o);                               \
  }

  LDSET(a0s0, a1s0, b0s0, b1s0, 0);
  LDSET(a0s1, a1s1, b0s1, b1s1, 1);
  __builtin_amdgcn_sched_barrier(0);
  // main rotation: nIter % 3 == 0 guaranteed (kLen = 3072 or 1536).
  // sched_barrier(0) after each LDSET: loads may NOT sink below the fence,
  // so the prefetch distance-2 schedule survives register allocation.
  for (int it = 0; it < nIter; it += 3) {
    LDSET(a0s2, a1s2, b0s2, b1s2, it + 2);
    __builtin_amdgcn_sched_barrier(0);
    MFMA4(a0s0, a1s0, b0s0, b1s0);
    LDSET(a0s0, a1s0, b0s0, b1s0, it + 3);
    __builtin_amdgcn_sched_barrier(0);
    MFMA4(a0s1, a1s1, b0s1, b1s1);
    LDSET(a0s1, a1s1, b0s1, b1s1, it + 4);
    __builtin_amdgcn_sched_barrier(0);
    MFMA4(a0s2, a1s2, b0s2, b1s2);
  }
#undef LDSET

  // C/D 32x32 layout: col = lane&31, row = (reg&3) + 8*(reg>>2) + 4*(lane>>5)
  for (int i = 0; i < 2; ++i) {
    int rb = rowBase + wr * 64 + i * 32 + 4 * hh;
    for (int j = 0; j < 2; ++j) {
      int cc = colBase + wc * 64 + j * 32 + r32;
      for (int reg = 0; reg < 16; ++reg) {
        int rr = rb + (reg & 3) + 8 * (reg >> 2);
        Cout[(size_t)rr * NN + cc] = bf16bits(acc[i][j][reg]);
      }
    }
  }
}

// ---------------------------------------------------------------------------
// post1: [0,768)     topk(A2 bf16 partial-sum) + packed fp8 cast -> A2f8
//        [768,1536)  tvec = A.y1 (one wave per row)
//        [1536,1920) concat uemb/iemb -> allE (aliases dead Af8)
__global__ __launch_bounds__(256) void post1(
    const unsigned short* __restrict__ C, int parts,
    const float* __restrict__ A, const float* __restrict__ y1,
    unsigned char* __restrict__ A2f8, int* __restrict__ cnts1,
    int* __restrict__ tIdx1, float* __restrict__ tVal1,
    float* __restrict__ tvec, const float* __restrict__ uemb,
    const float* __restrict__ iemb, float* __restrict__ allE) {
  const int bid = blockIdx.x;
  const int t = threadIdx.x;
  if (bid < 768) {
    int row = bid * 4 + (t >> 6);
    int lane = t & 63;
    float f[48];
    load48_bf(C, parts, row, lane, f);
    // fused packed fp8 cast: f[j*8+e] = col k0+e, k0=(j*64+lane)*8
#pragma unroll
    for (int j = 0; j < 6; ++j) {
      uint2 w;
      w.x = pk4_f8(f[j * 8 + 0] * F8SCALE2, f[j * 8 + 1] * F8SCALE2,
                   f[j * 8 + 2] * F8SCALE2, f[j * 8 + 3] * F8SCALE2);
      w.y = pk4_f8(f[j * 8 + 4] * F8SCALE2, f[j * 8 + 5] * F8SCALE2,
                   f[j * 8 + 6] * F8SCALE2, f[j * 8 + 7] * F8SCALE2);
      size_t addr = (size_t)(j * 8 + (lane >> 3)) * KBLK +
                    (size_t)row * 64 + (lane & 7) * 8;
      *(uint2*)(A2f8 + addr) = w;
    }
    select_compact(f, lane, DESCALE38, 1, &cnts1[row],
                   tIdx1 + (size_t)row * 128, tVal1 + (size_t)row * 128);
  } else if (bid < 1536) {
    int row = (bid - 768) * 4 + (t >> 6);
    int lane = t & 63;
    const float4* rp = (const float4*)(A + (size_t)row * NN);
    const float4* yp = (const float4*)y1;
    float s = 0.f;
#pragma unroll
    for (int j = 0; j < 12; ++j) {
      float4 a = rp[lane + j * 64];
      float4 y = yp[lane + j * 64];
      s += a.x * y.x + a.y * y.y + a.z * y.z + a.w * y.w;
    }
    for (int off = 32; off; off >>= 1) s += __shfl_down(s, off, 64);
    if (lane == 0) tvec[row] = s;
  } else {
    // concat embeddings into allE[NN][DD]; 384 blocks x 256 thr x float4
    int idx = (bid - 1536) * 256 + t;
    int e = idx * 4;
    float4 v = (e < NU * DD) ? *(const float4*)(uemb + e)
                             : *(const float4*)(iemb + (e - NU * DD));
    *(float4*)(allE + e) = v;
  }
}

// ---------------------------------------------------------------------------
// post2: single block -> w0..w3
__global__ __launch_bounds__(256) void post2(
    const float* __restrict__ vu, const float* __restrict__ vv,
    const float* __restrict__ y1, const float* __restrict__ s1,
    const float* __restrict__ tvec, float* __restrict__ wacc) {
  __shared__ float red4[4];
  const int t = threadIdx.x;
  float w0 = row_dot_f32(vu, vv, red4);  __syncthreads();
  float w1 = row_dot_f32(vu, y1, red4);  __syncthreads();
  float w2 = row_dot_f32(s1, y1, red4);  __syncthreads();
  float w3 = row_dot_f32(s1, tvec, red4);
  if (t == 0) { wacc[0] = w0; wacc[1] = w1; wacc[2] = w2; wacc[3] = w3; }
}

// ---------------------------------------------------------------------------
// sel02: phase-homogeneous select kernel (one select per wave, dense waves).
//   bid even: layer-2 lists from C (A3 bf16 partials) -> global
//   bid odd:  layer-0 lists from A (fp32)             -> global
// (interleaved so heavy/light blocks co-schedule; avoids the tail imbalance
// of a split-range grid). Lists land in the dead Atf8 buffer.
__global__ __launch_bounds__(256) void sel02(
    const unsigned short* __restrict__ C, int parts,
    const float* __restrict__ A, int* __restrict__ cnt0,
    int* __restrict__ idx0, float* __restrict__ val0,
    int* __restrict__ cnt2, int* __restrict__ idx2,
    float* __restrict__ val2) {
  const int bid = blockIdx.x;
  const int t = threadIdx.x;
  const int w = t >> 6, lane = t & 63;
  const int row = (bid >> 1) * 4 + w;
  float f[48];
  if ((bid & 1) == 0) {
    load48_bf(C, parts, row, lane, f);
    select_compact(f, lane, DESCALE38, 1, &cnt2[row],
                   idx2 + (size_t)row * 128, val2 + (size_t)row * 128);
  } else {
    load48_f32(A, row, lane, f);
    select_compact(f, lane, 1.0f, 0, &cnt0[row],
                   idx0 + (size_t)row * 128, val0 + (size_t)row * 128);
  }
}

// ---------------------------------------------------------------------------
// gather_light: pure gather, one wave per row (768 blocks x 256 thr).
// All three layer lists concatenated into one LDS run with the attention
// weights folded into the values at staging; float2 gather (64 lanes cover
// the 128 dims), 8 independent loads in flight, no __syncthreads.
__global__ __launch_bounds__(256) void gather_light(
    const float* __restrict__ allE, const float* __restrict__ uemb0,
    const float* __restrict__ iemb0, const float* __restrict__ wacc,
    const int* __restrict__ cnt0, const int* __restrict__ idx0,
    const float* __restrict__ val0, const int* __restrict__ cnts1,
    const int* __restrict__ tIdx1, const float* __restrict__ tVal1,
    const int* __restrict__ cnt2, const int* __restrict__ idx2,
    const float* __restrict__ val2, float* __restrict__ lightOut) {
  __shared__ int li[4][384];
  __shared__ float lv[4][384];
  const int t = threadIdx.x;
  const int w = t >> 6, lane = t & 63;
  const int row = blockIdx.x * 4 + w;

  float w0 = wacc[0], w1 = wacc[1], w2 = wacc[2], w3 = wacc[3];
  float ss = w0 + w1 + w2 + w3;
  w0 /= ss; w1 /= ss; w2 /= ss; w3 /= ss;
  float m = fmaxf(fmaxf(w0, w1), fmaxf(w2, w3));
  float ex0 = expf(w0 - m), ex1 = expf(w1 - m), ex2 = expf(w2 - m),
        ex3 = expf(w3 - m);
  float se = ex0 + ex1 + ex2 + ex3;
  float aw0 = ex0 / se, aw1 = ex1 / se, aw2 = ex2 / se, aw3 = ex3 / se;
  float aw4 = GAMMA_F * (aw1 + aw2 + aw3);

  const int c0 = cnt0[row], c1 = cnts1[row], c2 = cnt2[row];
  const int p0 = (c0 + 7) & ~7, p1 = (c1 + 7) & ~7, p2 = (c2 + 7) & ~7;
  int* Li = li[w];
  float* Lv = lv[w];
  const size_t rb = (size_t)row * 128;
  for (int k = lane; k < p0; k += 64) {
    bool in = k < c0;
    Li[k] = in ? idx0[rb + k] : 0;
    Lv[k] = in ? aw1 * val0[rb + k] : 0.f;
  }
  for (int k = lane; k < p1; k += 64) {
    bool in = k < c1;
    Li[p0 + k] = in ? tIdx1[rb + k] : 0;
    Lv[p0 + k] = in ? aw2 * tVal1[rb + k] : 0.f;
  }
  for (int k = lane; k < p2; k += 64) {
    bool in = k < c2;
    Li[p0 + p1 + k] = in ? idx2[rb + k] : 0;
    Lv[p0 + p1 + k] = in ? aw3 * val2[rb + k] : 0.f;
  }
  // same-wave produce->consume through LDS: compiler orders via lgkmcnt.

  const int ct = p0 + p1 + p2;
  const float2* E2 = (const float2*)allE;
  float ax = 0.f, ay = 0.f, bx_ = 0.f, by_ = 0.f;
  for (int k = 0; k < ct; k += 8) {
    int i0 = Li[k + 0], i1 = Li[k + 1], i2 = Li[k + 2], i3 = Li[k + 3];
    int i4 = Li[k + 4], i5 = Li[k + 5], i6 = Li[k + 6], i7 = Li[k + 7];
    float v0 = Lv[k + 0], v1 = Lv[k + 1], v2 = Lv[k + 2], v3 = Lv[k + 3];
    float v4 = Lv[k + 4], v5 = Lv[k + 5], v6 = Lv[k + 6], v7 = Lv[k + 7];
    float2 g0 = E2[(i0 >> 1) + lane];
    float2 g1 = E2[(i1 >> 1) + lane];
    float2 g2 = E2[(i2 >> 1) + lane];
    float2 g3 = E2[(i3 >> 1) + lane];
    float2 g4 = E2[(i4 >> 1) + lane];
    float2 g5 = E2[(i5 >> 1) + lane];
    float2 g6 = E2[(i6 >> 1) + lane];
    float2 g7 = E2[(i7 >> 1) + lane];
    ax += v0 * g0.x; ay += v0 * g0.y;
    bx_ += v1 * g1.x; by_ += v1 * g1.y;
    ax += v2 * g2.x; ay += v2 * g2.y;
    bx_ += v3 * g3.x; by_ += v3 * g3.y;
    ax += v4 * g4.x; ay += v4 * g4.y;
    bx_ += v5 * g5.x; by_ += v5 * g5.y;
    ax += v6 * g6.x; ay += v6 * g6.y;
    bx_ += v7 * g7.x; by_ += v7 * g7.y;
  }
  float2 sE = E2[((size_t)row << 6) + lane];
  float2 e0 = (row < NU)
                  ? ((const float2*)uemb0)[(size_t)row * 64 + lane]
                  : ((const float2*)iemb0)[(size_t)(row - NU) * 64 + lane];
  float ox = (ax + bx_) + aw0 * sE.x + aw4 * e0.x;
  float oy = (ay + by_) + aw0 * sE.y + aw4 * e0.y;
  float2 o; o.x = ox; o.y = oy;
  ((float2*)lightOut)[(size_t)row * 64 + lane] = o;
}

__global__ __launch_bounds__(256) void out_dot(const int* __restrict__ users,
                                               const int* __restrict__ items,
                                               const float* __restrict__ lightOut,
                                               float* __restrict__ out) {
  int b = blockIdx.x * 4 + (threadIdx.x >> 6);
  int lane = threadIdx.x & 63;
  const float* up = lightOut + (size_t)users[b] * DD;
  const float* ip = lightOut + (size_t)(NU + items[b]) * DD;
  float s = up[lane] * ip[lane] + up[lane + 64] * ip[lane + 64];
  for (int off = 32; off; off >>= 1) s += __shfl_down(s, off, 64);
  if (lane == 0) out[b] = s;
}

// ---------------------------------------------------------------------------
extern "C" void kernel_launch(void* const* d_in, const int* in_sizes, int n_in,
                              void* d_out, int out_size, void* d_ws,
                              size_t ws_size, hipStream_t stream) {
  const int* users = (const int*)d_in[0];
  const int* items = (const int*)d_in[1];
  const float* A = (const float*)d_in[2];
  const float* uemb = (const float*)d_in[3];
  const float* iemb = (const float*)d_in[4];
  const float* uemb0 = (const float*)d_in[5];
  const float* iemb0 = (const float*)d_in[6];
  const float* vu = (const float*)d_in[7];
  const float* vv = (const float*)d_in[8];
  float* out = (float*)d_out;

  char* ws = (char*)d_ws;
  size_t off = 0;
  auto alloc = [&](size_t bytes) -> void* {
    void* p = ws + off;
    off += (bytes + 255) & ~(size_t)255;
    return p;
  };
  unsigned char* Af8 = (unsigned char*)alloc((size_t)NN * NN);
  unsigned char* Atf8 = (unsigned char*)alloc((size_t)NN * NN);
  unsigned char* A2f8 = (unsigned char*)alloc((size_t)NN * NN);
  float* y1 = (float*)alloc((size_t)NN * 4);   // contiguous with s1
  float* s1 = (float*)alloc((size_t)NN * 4);
  float* tvec = (float*)alloc((size_t)NN * 4);
  float* wacc = (float*)alloc(256);
  int* cnts1 = (int*)alloc((size_t)NN * 4);
  int* tIdx1 = (int*)alloc((size_t)NN * 128 * 4);
  float* tVal1 = (float*)alloc((size_t)NN * 128 * 4);
  float* lightOut = (float*)alloc((size_t)NN * DD * 4);
  int* cnt0 = (int*)alloc((size_t)NN * 4);
  int* cnt2 = (int*)alloc((size_t)NN * 4);

  // allE (NN*DD fp32 = 1.5 MB) aliases Af8 (9.4 MB): Af8 is dead after
  // gemm#1 (step 3); post1 (step 4) writes allE; gather (step 8) reads.
  float* allE = (float*)Af8;
  // layer-0/2 lists (4 x 1.5 MB) alias Atf8 (9.4 MB): Atf8 is dead after
  // gemm#2 (step 5); sel02 (step 6) writes, gather (step 8) reads.
  const size_t LSTB = (size_t)NN * 128 * 4;
  int* idx0 = (int*)(Atf8);
  float* val0 = (float*)(Atf8 + LSTB);
  int* idx2 = (int*)(Atf8 + 2 * LSTB);
  float* val2 = (float*)(Atf8 + 3 * LSTB);

  const size_t cBytes = (size_t)NN * NN * 2;  // bf16 partials
  int kParts = (ws_size >= off + 2 * cBytes + 512) ? 2 : 1;
  unsigned short* C = (unsigned short*)alloc((size_t)kParts * cBytes);
  const int kLen = NN / kParts;

  // 1) zero y1/s1 (contiguous 2*NN floats)
  hipMemsetAsync(y1, 0, (size_t)2 * NN * 4, stream);
  // 2) prep: A -> packed fp8 (straight+transposed) + y1/s1 partials
  prep<<<2304, 256, 0, stream>>>(A, vu, vv, Af8, Atf8, y1, s1);
  // 3) A2 = A*A (pinned depth-2 pipeline + XCD swizzle, bf16 partials x2)
  gemm_f8<<<576 * kParts, 256, 0, stream>>>(Af8, Atf8, C, kLen);
  // 4) post1: topk(A2)+packed fp8 cast | tvec = A.y1 | emb concat -> allE
  post1<<<1920, 256, 0, stream>>>(C, kParts, A, y1, A2f8, cnts1, tIdx1,
                                  tVal1, tvec, uemb, iemb, allE);
  // 5) A3 = A2*A (overwrite partials)
  gemm_f8<<<576 * kParts, 256, 0, stream>>>(A2f8, Atf8, C, kLen);
  // 6) sel02: layer-0 (A) and layer-2 (A3) top-64 lists -> global (in Atf8)
  sel02<<<1536, 256, 0, stream>>>(C, kParts, A, cnt0, idx0, val0, cnt2, idx2,
                                  val2);
  // 7) post2: w0..w3 (single block)
  post2<<<1, 256, 0, stream>>>(vu, vv, y1, s1, tvec, wacc);
  // 8) gather_light: pure float2 gather, one wave per row
  gather_light<<<768, 256, 0, stream>>>(allE, uemb0, iemb0, wacc, cnt0, idx0,
                                        val0, cnts1, tIdx1, tVal1, cnt2, idx2,
                                        val2, lightOut);
  // 9) gather dots
  out_dot<<<BB / 4, 256, 0, stream>>>(users, items, lightOut, out);
}

// Round 6
// 263.885 us; speedup vs baseline: 1.2028x; 1.1972x over previous
//
#include <hip/hip_runtime.h>
#include <hip/hip_fp8.h>
#include <math.h>

#define NN 3072
#define NU 1024
#define NI 2048
#define DD 128
#define BB 8192
#define GAMMA_F 0.2f

#define SCALE_A 524288.0f                // 2^19
#define F8SCALE2 1.9073486328125e-06f    // 2^-19  (C*2^38 -> A2*2^19 for fp8)
#define DESCALE38 3.637978807091713e-12f // 2^-38  (C -> true A^k values)

// packed fp8 layout: [k/64][row][k%64]; one k-block = NN rows x 64 B
#define KBLK ((size_t)NN * 64)

typedef __attribute__((ext_vector_type(4))) float f32x4;
typedef __attribute__((ext_vector_type(16))) float f32x16;
typedef __attribute__((ext_vector_type(4))) int i32x4;
typedef __attribute__((ext_vector_type(8))) int i32x8;

static __device__ inline unsigned short bf16bits(float x) {
  union { unsigned u; float f; } cv;
  cv.f = x;
  unsigned r = cv.u + 0x7fff + ((cv.u >> 16) & 1);  // RNE
  return (unsigned short)(r >> 16);
}

// pack 4 floats -> 4 fp8 e4m3 (OCP) bytes
static __device__ inline unsigned pk4_f8(float a, float b, float c, float d) {
#if defined(__has_builtin)
#if __has_builtin(__builtin_amdgcn_cvt_pk_fp8_f32)
  int p = __builtin_amdgcn_cvt_pk_fp8_f32(a, b, 0, false);
  p = __builtin_amdgcn_cvt_pk_fp8_f32(c, d, p, true);
  return (unsigned)p;
#else
  return (unsigned)__hip_fp8_e4m3(a).__x | ((unsigned)__hip_fp8_e4m3(b).__x << 8) |
         ((unsigned)__hip_fp8_e4m3(c).__x << 16) |
         ((unsigned)__hip_fp8_e4m3(d).__x << 24);
#endif
#else
  return (unsigned)__hip_fp8_e4m3(a).__x | ((unsigned)__hip_fp8_e4m3(b).__x << 8) |
         ((unsigned)__hip_fp8_e4m3(c).__x << 16) |
         ((unsigned)__hip_fp8_e4m3(d).__x << 24);
#endif
}

static __device__ inline void atomAddF(float* p, float v) {
#if defined(__has_builtin)
#if __has_builtin(__builtin_amdgcn_global_atomic_fadd_f32)
  __builtin_amdgcn_global_atomic_fadd_f32(
      (__attribute__((address_space(1))) float*)p, v);
#else
  unsafeAtomicAdd(p, v);
#endif
#else
  unsafeAtomicAdd(p, v);
#endif
}

static __device__ inline float block_sum(float s, float* red4) {
  int tid = threadIdx.x;
  for (int off = 32; off; off >>= 1) s += __shfl_down(s, off, 64);
  if ((tid & 63) == 0) red4[tid >> 6] = s;
  __syncthreads();
  return red4[0] + red4[1] + red4[2] + red4[3];
}

static __device__ inline float row_dot_f32(const float* __restrict__ a,
                                           const float* __restrict__ b,
                                           float* red4) {
  const float4* ap = (const float4*)a;
  const float4* bp = (const float4*)b;
  float s = 0.f;
  for (int j = threadIdx.x; j < NN / 4; j += 256) {
    float4 x = ap[j], y = bp[j];
    s += x.x * y.x + x.y * y.y + x.z * y.z + x.w * y.w;
  }
  return block_sum(s, red4);
}

// ---------------------------------------------------------------------------
// topk loaders: fill f[48] with this row's values (one wave, 48 vals/lane).
static __device__ inline void load48_bf(const unsigned short* __restrict__ b0,
                                        int parts, int row, int lane,
                                        float* f) {
  const uint4* r0 = (const uint4*)(b0 + (size_t)row * NN);
#pragma unroll
  for (int j = 0; j < 6; ++j) {
    uint4 q = r0[lane + j * 64];
    unsigned uu[4] = {q.x, q.y, q.z, q.w};
#pragma unroll
    for (int e = 0; e < 4; ++e) {
      f[j * 8 + e * 2] = __uint_as_float(uu[e] << 16);
      f[j * 8 + e * 2 + 1] = __uint_as_float(uu[e] & 0xffff0000u);
    }
  }
  for (int p = 1; p < parts; ++p) {
    const uint4* rp = (const uint4*)(b0 + (size_t)p * NN * NN + (size_t)row * NN);
#pragma unroll
    for (int j = 0; j < 6; ++j) {
      uint4 q = rp[lane + j * 64];
      unsigned uu[4] = {q.x, q.y, q.z, q.w};
#pragma unroll
      for (int e = 0; e < 4; ++e) {
        f[j * 8 + e * 2] += __uint_as_float(uu[e] << 16);
        f[j * 8 + e * 2 + 1] += __uint_as_float(uu[e] & 0xffff0000u);
      }
    }
  }
}

static __device__ inline void load48_f32(const float* __restrict__ A, int row,
                                         int lane, float* f) {
  const float4* r0 = (const float4*)(A + (size_t)row * NN);
#pragma unroll
  for (int j = 0; j < 12; ++j) {
    float4 a = r0[lane + j * 64];
    f[j * 4 + 0] = a.x; f[j * 4 + 1] = a.y;
    f[j * 4 + 2] = a.z; f[j * 4 + 3] = a.w;
  }
}

// ---------------------------------------------------------------------------
// select top-64 of the wave's 64x48 values. Radix on bits [30..16] resolved
// TWO bits per step (counts are monotone c3<=c2<=c1, so "largest 2-bit
// pattern with count>=64" == two greedy single-bit steps) with butterfly
// shfl_xor reduces (all lanes end with the total -> no broadcast). Compact
// (idx*DD, val*scale) into out arrays (128 slots; LDS or global).
static __device__ void select_compact(const float* f, int lane, float descale,
                                      int bf, int* __restrict__ outCnt,
                                      int* __restrict__ outIdx,
                                      float* __restrict__ outVal) {
  unsigned bor = 0, band = 0xffffffffu;
#pragma unroll
  for (int r = 0; r < 48; ++r) {
    unsigned k = __float_as_uint(f[r]);
    bor |= k; band &= k;
  }
  for (int off = 32; off; off >>= 1) {
    bor |= (unsigned)__shfl_xor((int)bor, off, 64);
    band &= (unsigned)__shfl_xor((int)band, off, 64);
  }
  unsigned diff = bor ^ band;
  int hi = diff ? (31 - __clz(diff)) : 16;
  if (hi < 16) hi = 16;
  if (hi > 30) hi = 30;
  unsigned t = band & ~((2u << hi) - 1u);

  int b = hi;
  while (b >= 17) {
    unsigned base = 1u << (b - 1);
    unsigned cand1 = t | base;
    unsigned cand2 = t | (base << 1);
    unsigned cand3 = cand2 | base;
    int c1 = 0, c2 = 0, c3 = 0;
#pragma unroll
    for (int r = 0; r < 48; ++r) {
      unsigned k = __float_as_uint(f[r]);
      c1 += (k >= cand1) ? 1 : 0;
      c2 += (k >= cand2) ? 1 : 0;
      c3 += (k >= cand3) ? 1 : 0;
    }
    for (int off = 32; off; off >>= 1) {
      c1 += __shfl_xor(c1, off, 64);
      c2 += __shfl_xor(c2, off, 64);
      c3 += __shfl_xor(c3, off, 64);
    }
    if (c3 >= 64) t = cand3;
    else if (c2 >= 64) t = cand2;
    else if (c1 >= 64) t = cand1;
    b -= 2;
  }
  if (b == 16) {
    unsigned cand = t | (1u << 16);
    int c = 0;
#pragma unroll
    for (int r = 0; r < 48; ++r) c += (__float_as_uint(f[r]) >= cand) ? 1 : 0;
    for (int off = 32; off; off >>= 1) c += __shfl_xor(c, off, 64);
    if (c >= 64) t = cand;
  }

  int basec = 0;
#pragma unroll
  for (int r = 0; r < 48; ++r) {
    bool keep = __float_as_uint(f[r]) >= t;
    unsigned long long m = __ballot(keep);
    if (keep) {
      int pos = basec + __popcll(m & ((1ull << lane) - 1ull));
      if (pos < 128) {
        int col = bf ? ((r >> 3) * 512 + lane * 8 + (r & 7))
                     : ((r >> 2) * 256 + lane * 4 + (r & 3));
        outIdx[pos] = col << 7;  // pre-scaled by DD for gather addressing
        outVal[pos] = f[r] * descale;
      }
    }
    basec += __popcll(m);
  }
  if (lane == 0) *outCnt = basec < 128 ? basec : 128;
}

// ---------------------------------------------------------------------------
// prep: A -> fp8 PACKED (straight + transposed, x2^19) + fused y1/s1 matvec
// partials. grid 2304 (48x48 tiles of 64x64).
__global__ __launch_bounds__(256) void prep(
    const float* __restrict__ A, const float* __restrict__ vu,
    const float* __restrict__ vv, unsigned char* __restrict__ Af8,
    unsigned char* __restrict__ Atf8, float* __restrict__ y1,
    float* __restrict__ s1) {
  __shared__ float sh[64 * 65 + 512];
  const int bid = blockIdx.x;
  const int t = threadIdx.x;
  const int bx = (bid % 48) * 64, by = (bid / 48) * 64;
  const int rr = t >> 4;
  const int c4 = (t & 15) * 4;
  for (int it = 0; it < 4; ++it) {
    int r = rr + it * 16;
    float4 val = *(const float4*)(A + (size_t)(by + r) * NN + bx + c4);
    sh[r * 65 + c4] = val.x; sh[r * 65 + c4 + 1] = val.y;
    sh[r * 65 + c4 + 2] = val.z; sh[r * 65 + c4 + 3] = val.w;
  }
  __syncthreads();
  {
    int row = t >> 2, ch = t & 3;
    const float* sp = &sh[row * 65 + ch * 16];
    uint4 w;
    w.x = pk4_f8(sp[0] * SCALE_A, sp[1] * SCALE_A, sp[2] * SCALE_A,
                 sp[3] * SCALE_A);
    w.y = pk4_f8(sp[4] * SCALE_A, sp[5] * SCALE_A, sp[6] * SCALE_A,
                 sp[7] * SCALE_A);
    w.z = pk4_f8(sp[8] * SCALE_A, sp[9] * SCALE_A, sp[10] * SCALE_A,
                 sp[11] * SCALE_A);
    w.w = pk4_f8(sp[12] * SCALE_A, sp[13] * SCALE_A, sp[14] * SCALE_A,
                 sp[15] * SCALE_A);
    *(uint4*)(Af8 + (size_t)(bx >> 6) * KBLK + (size_t)(by + row) * 64 +
              ch * 16) = w;
  }
  {
    int c = t >> 2, ch = t & 3;
    float v[16];
#pragma unroll
    for (int e = 0; e < 16; ++e) v[e] = sh[(ch * 16 + e) * 65 + c];
    uint4 w;
    w.x = pk4_f8(v[0] * SCALE_A, v[1] * SCALE_A, v[2] * SCALE_A,
                 v[3] * SCALE_A);
    w.y = pk4_f8(v[4] * SCALE_A, v[5] * SCALE_A, v[6] * SCALE_A,
                 v[7] * SCALE_A);
    w.z = pk4_f8(v[8] * SCALE_A, v[9] * SCALE_A, v[10] * SCALE_A,
                 v[11] * SCALE_A);
    w.w = pk4_f8(v[12] * SCALE_A, v[13] * SCALE_A, v[14] * SCALE_A,
                 v[15] * SCALE_A);
    *(uint4*)(Atf8 + (size_t)(by >> 6) * KBLK + (size_t)(bx + c) * 64 +
              ch * 16) = w;
  }
  const int q = t >> 6;
  const int l = t & 63;
  float sy = 0.f, ss_ = 0.f;
  for (int i = 0; i < 16; ++i) {
    int c = q * 16 + i;
    sy += sh[l * 65 + c] * vv[bx + c];
    ss_ += vu[by + c] * sh[c * 65 + l];
  }
  float* red = sh + 64 * 65;
  red[q * 64 + l] = sy;
  red[256 + q * 64 + l] = ss_;
  __syncthreads();
  if (t < 64) {
    float v4 = red[t] + red[64 + t] + red[128 + t] + red[192 + t];
    atomAddF(&y1[by + t], v4);
  } else if (t < 128) {
    int cc = t - 64;
    float v4 = red[256 + cc] + red[256 + 64 + cc] + red[256 + 128 + cc] +
               red[256 + 192 + cc];
    atomAddF(&s1[bx + cc], v4);
  }
}

// ---------------------------------------------------------------------------
// gemm_f8 v7: LDS double-buffered 2-phase pipeline with global_load_lds
// (the guide's m97/T3-minimum structure — reg-direct pipelining proved
// unpinnable in v5/v6). 128x128 tile, BK=64, 4 waves (2x2), 32 KB LDS.
//
// Fragment-linear LDS layout: 16 chunks x 1 KB per buffer. Chunk q (q<8 = A,
// q>=8 = B; s=(q>>1)&3 row-subtile, h=q&1 16B-half) holds, at lane offset
// l*16, the global bytes {row = base + s*32 + (l&31), bytes (l>>5)*32+h*16}
// — exactly the MFMA operand bytes for lane l. ds_read_b128 at l*16 is the
// canonical conflict-free pattern; the "swizzle" lives entirely in the
// per-lane GLOBAL source address (rule #21: source-side pre-swizzle).
//
// XCD column-ownership swizzle: each XCD owns 3 B-column panels (1.1 MB,
// L2-resident for the whole GEMM); A streams from L3 (v6's row-chunk swizzle
// needed all of B per XCD -> L2 thrash, FETCH 43->90 MB; this reverses it).
#define MFMA4(A0, A1, B0, B1)                                          \
  acc[0][0] = __builtin_amdgcn_mfma_scale_f32_32x32x64_f8f6f4(         \
      A0, B0, acc[0][0], 0, 0, 0, 127, 0, 127);                        \
  acc[0][1] = __builtin_amdgcn_mfma_scale_f32_32x32x64_f8f6f4(         \
      A0, B1, acc[0][1], 0, 0, 0, 127, 0, 127);                        \
  acc[1][0] = __builtin_amdgcn_mfma_scale_f32_32x32x64_f8f6f4(         \
      A1, B0, acc[1][0], 0, 0, 0, 127, 0, 127);                        \
  acc[1][1] = __builtin_amdgcn_mfma_scale_f32_32x32x64_f8f6f4(         \
      A1, B1, acc[1][1], 0, 0, 0, 127, 0, 127);

static __device__ inline i32x8 ldfragL(const char* p) {
  i32x4 lo = *(const i32x4*)p;
  i32x4 hi = *(const i32x4*)(p + 1024);
  return (i32x8){lo.x, lo.y, lo.z, lo.w, hi.x, hi.y, hi.z, hi.w};
}

__global__ __launch_bounds__(256) void gemm_f8(
    const unsigned char* __restrict__ Ag,
    const unsigned char* __restrict__ Btg,
    unsigned short* __restrict__ Cg) {
  __shared__ char smem[2][16384];
  // XCD column-ownership swizzle (bijective over 576 = 8 XCD x 3 col x 24 row)
  const int wg = blockIdx.x;
  const int xcd = wg & 7;
  const int idx = wg >> 3;                 // 0..71
  const int bxi = xcd * 3 + (idx % 3);     // column panel
  const int byi = idx / 3;                 // row panel
  const int rowBase = byi * 128, colBase = bxi * 128;

  const int t = threadIdx.x;
  const int w = t >> 6, l = t & 63;
  const int wr = w >> 1, wc = w & 1;
  const int r32 = l & 31, hh = l >> 5;

  f32x16 acc[2][2];
  for (int i = 0; i < 2; ++i)
    for (int j = 0; j < 2; ++j)
      for (int e = 0; e < 16; ++e) acc[i][j][e] = 0.f;

  const unsigned char* aT = Ag + (size_t)rowBase * 64;
  const unsigned char* bT = Btg + (size_t)colBase * 64;
  // per-lane source offset within a chunk's 32-row group
  const int laneOff = r32 * 64 + hh * 32;

#define STAGE(kt, b)                                                        \
  {                                                                         \
    const size_t kOff = (size_t)(kt) * KBLK;                                \
    _Pragma("unroll") for (int r_ = 0; r_ < 4; ++r_) {                      \
      int q_ = r_ * 4 + w;                                                  \
      int s_ = (q_ >> 1) & 3, h_ = q_ & 1;                                  \
      const unsigned char* g_ = ((q_ < 8) ? aT : bT) + kOff +               \
                                (size_t)(s_ * 32) * 64 + laneOff + h_ * 16; \
      __builtin_amdgcn_global_load_lds(                                     \
          (const __attribute__((address_space(1))) unsigned*)g_,            \
          (__attribute__((address_space(3))) unsigned*)(smem[b] +           \
                                                        q_ * 1024),         \
          16, 0, 0);                                                        \
    }                                                                       \
  }

  const int nt = NN / 64;  // 48
  STAGE(0, 0);
  __syncthreads();
  int cur = 0;
  for (int kt = 0; kt < nt; ++kt) {
    if (kt + 1 < nt) STAGE(kt + 1, cur ^ 1);
    const char* sb = smem[cur];
    i32x8 a0 = ldfragL(sb + (wr * 2 + 0) * 2048 + l * 16);
    i32x8 a1 = ldfragL(sb + (wr * 2 + 1) * 2048 + l * 16);
    i32x8 b0 = ldfragL(sb + 8192 + (wc * 2 + 0) * 2048 + l * 16);
    i32x8 b1 = ldfragL(sb + 8192 + (wc * 2 + 1) * 2048 + l * 16);
    MFMA4(a0, a1, b0, b1);
    __syncthreads();  // drains vmcnt (next-tile stage) + lgkm; flips safe
    cur ^= 1;
  }
#undef STAGE

  // C/D 32x32 layout: col = lane&31, row = (reg&3) + 8*(reg>>2) + 4*(lane>>5)
  for (int i = 0; i < 2; ++i) {
    int rb = rowBase + wr * 64 + i * 32 + 4 * hh;
    for (int j = 0; j < 2; ++j) {
      int cc = colBase + wc * 64 + j * 32 + r32;
      for (int reg = 0; reg < 16; ++reg) {
        int rr = rb + (reg & 3) + 8 * (reg >> 2);
        Cg[(size_t)rr * NN + cc] = bf16bits(acc[i][j][reg]);
      }
    }
  }
}

// ---------------------------------------------------------------------------
// post1: [0,768)     topk(A2 bf16) + packed fp8 cast -> A2f8
//        [768,1536)  tvec = A.y1 (one wave per row)
//        [1536,1920) concat uemb/iemb -> allE (aliases dead Af8)
__global__ __launch_bounds__(256) void post1(
    const unsigned short* __restrict__ C, int parts,
    const float* __restrict__ A, const float* __restrict__ y1,
    unsigned char* __restrict__ A2f8, int* __restrict__ cnts1,
    int* __restrict__ tIdx1, float* __restrict__ tVal1,
    float* __restrict__ tvec, const float* __restrict__ uemb,
    const float* __restrict__ iemb, float* __restrict__ allE) {
  const int bid = blockIdx.x;
  const int t = threadIdx.x;
  if (bid < 768) {
    int row = bid * 4 + (t >> 6);
    int lane = t & 63;
    float f[48];
    load48_bf(C, parts, row, lane, f);
    // fused packed fp8 cast: f[j*8+e] = col k0+e, k0=(j*64+lane)*8
#pragma unroll
    for (int j = 0; j < 6; ++j) {
      uint2 w;
      w.x = pk4_f8(f[j * 8 + 0] * F8SCALE2, f[j * 8 + 1] * F8SCALE2,
                   f[j * 8 + 2] * F8SCALE2, f[j * 8 + 3] * F8SCALE2);
      w.y = pk4_f8(f[j * 8 + 4] * F8SCALE2, f[j * 8 + 5] * F8SCALE2,
                   f[j * 8 + 6] * F8SCALE2, f[j * 8 + 7] * F8SCALE2);
      size_t addr = (size_t)(j * 8 + (lane >> 3)) * KBLK +
                    (size_t)row * 64 + (lane & 7) * 8;
      *(uint2*)(A2f8 + addr) = w;
    }
    select_compact(f, lane, DESCALE38, 1, &cnts1[row],
                   tIdx1 + (size_t)row * 128, tVal1 + (size_t)row * 128);
  } else if (bid < 1536) {
    int row = (bid - 768) * 4 + (t >> 6);
    int lane = t & 63;
    const float4* rp = (const float4*)(A + (size_t)row * NN);
    const float4* yp = (const float4*)y1;
    float s = 0.f;
#pragma unroll
    for (int j = 0; j < 12; ++j) {
      float4 a = rp[lane + j * 64];
      float4 y = yp[lane + j * 64];
      s += a.x * y.x + a.y * y.y + a.z * y.z + a.w * y.w;
    }
    for (int off = 32; off; off >>= 1) s += __shfl_down(s, off, 64);
    if (lane == 0) tvec[row] = s;
  } else {
    // concat embeddings into allE[NN][DD]; 384 blocks x 256 thr x float4
    int idx = (bid - 1536) * 256 + t;
    int e = idx * 4;
    float4 v = (e < NU * DD) ? *(const float4*)(uemb + e)
                             : *(const float4*)(iemb + (e - NU * DD));
    *(float4*)(allE + e) = v;
  }
}

// ---------------------------------------------------------------------------
// post2: single block -> w0..w3
__global__ __launch_bounds__(256) void post2(
    const float* __restrict__ vu, const float* __restrict__ vv,
    const float* __restrict__ y1, const float* __restrict__ s1,
    const float* __restrict__ tvec, float* __restrict__ wacc) {
  __shared__ float red4[4];
  const int t = threadIdx.x;
  float w0 = row_dot_f32(vu, vv, red4);  __syncthreads();
  float w1 = row_dot_f32(vu, y1, red4);  __syncthreads();
  float w2 = row_dot_f32(s1, y1, red4);  __syncthreads();
  float w3 = row_dot_f32(s1, tvec, red4);
  if (t == 0) { wacc[0] = w0; wacc[1] = w1; wacc[2] = w2; wacc[3] = w3; }
}

// ---------------------------------------------------------------------------
// sel02: phase-homogeneous select kernel (one select per wave, dense waves).
//   bid even: layer-2 lists from C (A3 bf16) -> global
//   bid odd:  layer-0 lists from A (fp32)    -> global
// Lists land in the dead Atf8 buffer.
__global__ __launch_bounds__(256) void sel02(
    const unsigned short* __restrict__ C, int parts,
    const float* __restrict__ A, int* __restrict__ cnt0,
    int* __restrict__ idx0, float* __restrict__ val0,
    int* __restrict__ cnt2, int* __restrict__ idx2,
    float* __restrict__ val2) {
  const int bid = blockIdx.x;
  const int t = threadIdx.x;
  const int w = t >> 6, lane = t & 63;
  const int row = (bid >> 1) * 4 + w;
  float f[48];
  if ((bid & 1) == 0) {
    load48_bf(C, parts, row, lane, f);
    select_compact(f, lane, DESCALE38, 1, &cnt2[row],
                   idx2 + (size_t)row * 128, val2 + (size_t)row * 128);
  } else {
    load48_f32(A, row, lane, f);
    select_compact(f, lane, 1.0f, 0, &cnt0[row],
                   idx0 + (size_t)row * 128, val0 + (size_t)row * 128);
  }
}

// ---------------------------------------------------------------------------
// gather_light: pure gather, one wave per row (768 blocks x 256 thr).
// All three layer lists concatenated into one LDS run with the attention
// weights folded into the values at staging; float2 gather (64 lanes cover
// the 128 dims), 8 independent loads in flight, no __syncthreads.
__global__ __launch_bounds__(256) void gather_light(
    const float* __restrict__ allE, const float* __restrict__ uemb0,
    const float* __restrict__ iemb0, const float* __restrict__ wacc,
    const int* __restrict__ cnt0, const int* __restrict__ idx0,
    const float* __restrict__ val0, const int* __restrict__ cnts1,
    const int* __restrict__ tIdx1, const float* __restrict__ tVal1,
    const int* __restrict__ cnt2, const int* __restrict__ idx2,
    const float* __restrict__ val2, float* __restrict__ lightOut) {
  __shared__ int li[4][384];
  __shared__ float lv[4][384];
  const int t = threadIdx.x;
  const int w = t >> 6, lane = t & 63;
  const int row = blockIdx.x * 4 + w;

  float w0 = wacc[0], w1 = wacc[1], w2 = wacc[2], w3 = wacc[3];
  float ss = w0 + w1 + w2 + w3;
  w0 /= ss; w1 /= ss; w2 /= ss; w3 /= ss;
  float m = fmaxf(fmaxf(w0, w1), fmaxf(w2, w3));
  float ex0 = expf(w0 - m), ex1 = expf(w1 - m), ex2 = expf(w2 - m),
        ex3 = expf(w3 - m);
  float se = ex0 + ex1 + ex2 + ex3;
  float aw0 = ex0 / se, aw1 = ex1 / se, aw2 = ex2 / se, aw3 = ex3 / se;
  float aw4 = GAMMA_F * (aw1 + aw2 + aw3);

  const int c0 = cnt0[row], c1 = cnts1[row], c2 = cnt2[row];
  const int p0 = (c0 + 7) & ~7, p1 = (c1 + 7) & ~7, p2 = (c2 + 7) & ~7;
  int* Li = li[w];
  float* Lv = lv[w];
  const size_t rb = (size_t)row * 128;
  for (int k = lane; k < p0; k += 64) {
    bool in = k < c0;
    Li[k] = in ? idx0[rb + k] : 0;
    Lv[k] = in ? aw1 * val0[rb + k] : 0.f;
  }
  for (int k = lane; k < p1; k += 64) {
    bool in = k < c1;
    Li[p0 + k] = in ? tIdx1[rb + k] : 0;
    Lv[p0 + k] = in ? aw2 * tVal1[rb + k] : 0.f;
  }
  for (int k = lane; k < p2; k += 64) {
    bool in = k < c2;
    Li[p0 + p1 + k] = in ? idx2[rb + k] : 0;
    Lv[p0 + p1 + k] = in ? aw3 * val2[rb + k] : 0.f;
  }
  // same-wave produce->consume through LDS: compiler orders via lgkmcnt.

  const int ct = p0 + p1 + p2;
  const float2* E2 = (const float2*)allE;
  float ax = 0.f, ay = 0.f, bx_ = 0.f, by_ = 0.f;
  for (int k = 0; k < ct; k += 8) {
    int i0 = Li[k + 0], i1 = Li[k + 1], i2 = Li[k + 2], i3 = Li[k + 3];
    int i4 = Li[k + 4], i5 = Li[k + 5], i6 = Li[k + 6], i7 = Li[k + 7];
    float v0 = Lv[k + 0], v1 = Lv[k + 1], v2 = Lv[k + 2], v3 = Lv[k + 3];
    float v4 = Lv[k + 4], v5 = Lv[k + 5], v6 = Lv[k + 6], v7 = Lv[k + 7];
    float2 g0 = E2[(i0 >> 1) + lane];
    float2 g1 = E2[(i1 >> 1) + lane];
    float2 g2 = E2[(i2 >> 1) + lane];
    float2 g3 = E2[(i3 >> 1) + lane];
    float2 g4 = E2[(i4 >> 1) + lane];
    float2 g5 = E2[(i5 >> 1) + lane];
    float2 g6 = E2[(i6 >> 1) + lane];
    float2 g7 = E2[(i7 >> 1) + lane];
    ax += v0 * g0.x; ay += v0 * g0.y;
    bx_ += v1 * g1.x; by_ += v1 * g1.y;
    ax += v2 * g2.x; ay += v2 * g2.y;
    bx_ += v3 * g3.x; by_ += v3 * g3.y;
    ax += v4 * g4.x; ay += v4 * g4.y;
    bx_ += v5 * g5.x; by_ += v5 * g5.y;
    ax += v6 * g6.x; ay += v6 * g6.y;
    bx_ += v7 * g7.x; by_ += v7 * g7.y;
  }
  float2 sE = E2[((size_t)row << 6) + lane];
  float2 e0 = (row < NU)
                  ? ((const float2*)uemb0)[(size_t)row * 64 + lane]
                  : ((const float2*)iemb0)[(size_t)(row - NU) * 64 + lane];
  float ox = (ax + bx_) + aw0 * sE.x + aw4 * e0.x;
  float oy = (ay + by_) + aw0 * sE.y + aw4 * e0.y;
  float2 o; o.x = ox; o.y = oy;
  ((float2*)lightOut)[(size_t)row * 64 + lane] = o;
}

__global__ __launch_bounds__(256) void out_dot(const int* __restrict__ users,
                                               const int* __restrict__ items,
                                               const float* __restrict__ lightOut,
                                               float* __restrict__ out) {
  int b = blockIdx.x * 4 + (threadIdx.x >> 6);
  int lane = threadIdx.x & 63;
  const float* up = lightOut + (size_t)users[b] * DD;
  const float* ip = lightOut + (size_t)(NU + items[b]) * DD;
  float s = up[lane] * ip[lane] + up[lane + 64] * ip[lane + 64];
  for (int off = 32; off; off >>= 1) s += __shfl_down(s, off, 64);
  if (lane == 0) out[b] = s;
}

// ---------------------------------------------------------------------------
extern "C" void kernel_launch(void* const* d_in, const int* in_sizes, int n_in,
                              void* d_out, int out_size, void* d_ws,
                              size_t ws_size, hipStream_t stream) {
  const int* users = (const int*)d_in[0];
  const int* items = (const int*)d_in[1];
  const float* A = (const float*)d_in[2];
  const float* uemb = (const float*)d_in[3];
  const float* iemb = (const float*)d_in[4];
  const float* uemb0 = (const float*)d_in[5];
  const float* iemb0 = (const float*)d_in[6];
  const float* vu = (const float*)d_in[7];
  const float* vv = (const float*)d_in[8];
  float* out = (float*)d_out;

  char* ws = (char*)d_ws;
  size_t off = 0;
  auto alloc = [&](size_t bytes) -> void* {
    void* p = ws + off;
    off += (bytes + 255) & ~(size_t)255;
    return p;
  };
  unsigned char* Af8 = (unsigned char*)alloc((size_t)NN * NN);
  unsigned char* Atf8 = (unsigned char*)alloc((size_t)NN * NN);
  unsigned char* A2f8 = (unsigned char*)alloc((size_t)NN * NN);
  float* y1 = (float*)alloc((size_t)NN * 4);   // contiguous with s1
  float* s1 = (float*)alloc((size_t)NN * 4);
  float* tvec = (float*)alloc((size_t)NN * 4);
  float* wacc = (float*)alloc(256);
  int* cnts1 = (int*)alloc((size_t)NN * 4);
  int* tIdx1 = (int*)alloc((size_t)NN * 128 * 4);
  float* tVal1 = (float*)alloc((size_t)NN * 128 * 4);
  float* lightOut = (float*)alloc((size_t)NN * DD * 4);
  int* cnt0 = (int*)alloc((size_t)NN * 4);
  int* cnt2 = (int*)alloc((size_t)NN * 4);

  // allE (NN*DD fp32 = 1.5 MB) aliases Af8 (9.4 MB): Af8 is dead after
  // gemm#1 (step 3); post1 (step 4) writes allE; gather (step 8) reads.
  float* allE = (float*)Af8;
  // layer-0/2 lists (4 x 1.5 MB) alias Atf8 (9.4 MB): Atf8 is dead after
  // gemm#2 (step 5); sel02 (step 6) writes, gather (step 8) reads.
  const size_t LSTB = (size_t)NN * 128 * 4;
  int* idx0 = (int*)(Atf8);
  float* val0 = (float*)(Atf8 + LSTB);
  int* idx2 = (int*)(Atf8 + 2 * LSTB);
  float* val2 = (float*)(Atf8 + 3 * LSTB);

  // single-part bf16 C (the pipelined GEMM needs no K-split; halves C I/O)
  unsigned short* C = (unsigned short*)alloc((size_t)NN * NN * 2);

  // 1) zero y1/s1 (contiguous 2*NN floats)
  hipMemsetAsync(y1, 0, (size_t)2 * NN * 4, stream);
  // 2) prep: A -> packed fp8 (straight+transposed) + y1/s1 partials
  prep<<<2304, 256, 0, stream>>>(A, vu, vv, Af8, Atf8, y1, s1);
  // 3) A2 = A*A (LDS 2-phase pipelined MX fp8 MFMA)
  gemm_f8<<<576, 256, 0, stream>>>(Af8, Atf8, C);
  // 4) post1: topk(A2)+packed fp8 cast | tvec = A.y1 | emb concat -> allE
  post1<<<1920, 256, 0, stream>>>(C, 1, A, y1, A2f8, cnts1, tIdx1,
                                  tVal1, tvec, uemb, iemb, allE);
  // 5) A3 = A2*A (overwrite C)
  gemm_f8<<<576, 256, 0, stream>>>(A2f8, Atf8, C);
  // 6) sel02: layer-0 (A) and layer-2 (A3) top-64 lists -> global (in Atf8)
  sel02<<<1536, 256, 0, stream>>>(C, 1, A, cnt0, idx0, val0, cnt2, idx2,
                                  val2);
  // 7) post2: w0..w3 (single block)
  post2<<<1, 256, 0, stream>>>(vu, vv, y1, s1, tvec, wacc);
  // 8) gather_light: pure float2 gather, one wave per row
  gather_light<<<768, 256, 0, stream>>>(allE, uemb0, iemb0, wacc, cnt0, idx0,
                                        val0, cnts1, tIdx1, tVal1, cnt2, idx2,
                                        val2, lightOut);
  // 9) gather dots
  out_dot<<<BB / 4, 256, 0, stream>>>(users, items, lightOut, out);
}

// Round 7
// 259.031 us; speedup vs baseline: 1.2254x; 1.0187x over previous
//
#include <hip/hip_runtime.h>
#include <hip/hip_fp8.h>
#include <math.h>

#define NN 3072
#define NU 1024
#define NI 2048
#define DD 128
#define BB 8192
#define GAMMA_F 0.2f

#define SCALE_A 524288.0f                // 2^19
#define F8SCALE2 1.9073486328125e-06f    // 2^-19  (C*2^38 -> A2*2^19 for fp8)
#define DESCALE38 3.637978807091713e-12f // 2^-38  (C -> true A^k values)

// packed fp8 layout: [k/64][row][k%64]; one k-block = NN rows x 64 B
#define KBLK ((size_t)NN * 64)

typedef __attribute__((ext_vector_type(4))) float f32x4;
typedef __attribute__((ext_vector_type(16))) float f32x16;
typedef __attribute__((ext_vector_type(4))) int i32x4;
typedef __attribute__((ext_vector_type(8))) int i32x8;

static __device__ inline unsigned short bf16bits(float x) {
  union { unsigned u; float f; } cv;
  cv.f = x;
  unsigned r = cv.u + 0x7fff + ((cv.u >> 16) & 1);  // RNE
  return (unsigned short)(r >> 16);
}

// pack 4 floats -> 4 fp8 e4m3 (OCP) bytes
static __device__ inline unsigned pk4_f8(float a, float b, float c, float d) {
#if defined(__has_builtin)
#if __has_builtin(__builtin_amdgcn_cvt_pk_fp8_f32)
  int p = __builtin_amdgcn_cvt_pk_fp8_f32(a, b, 0, false);
  p = __builtin_amdgcn_cvt_pk_fp8_f32(c, d, p, true);
  return (unsigned)p;
#else
  return (unsigned)__hip_fp8_e4m3(a).__x | ((unsigned)__hip_fp8_e4m3(b).__x << 8) |
         ((unsigned)__hip_fp8_e4m3(c).__x << 16) |
         ((unsigned)__hip_fp8_e4m3(d).__x << 24);
#endif
#else
  return (unsigned)__hip_fp8_e4m3(a).__x | ((unsigned)__hip_fp8_e4m3(b).__x << 8) |
         ((unsigned)__hip_fp8_e4m3(c).__x << 16) |
         ((unsigned)__hip_fp8_e4m3(d).__x << 24);
#endif
}

static __device__ inline void atomAddF(float* p, float v) {
#if defined(__has_builtin)
#if __has_builtin(__builtin_amdgcn_global_atomic_fadd_f32)
  __builtin_amdgcn_global_atomic_fadd_f32(
      (__attribute__((address_space(1))) float*)p, v);
#else
  unsafeAtomicAdd(p, v);
#endif
#else
  unsafeAtomicAdd(p, v);
#endif
}

static __device__ inline float block_sum(float s, float* red4) {
  int tid = threadIdx.x;
  for (int off = 32; off; off >>= 1) s += __shfl_down(s, off, 64);
  if ((tid & 63) == 0) red4[tid >> 6] = s;
  __syncthreads();
  return red4[0] + red4[1] + red4[2] + red4[3];
}

static __device__ inline float row_dot_f32(const float* __restrict__ a,
                                           const float* __restrict__ b,
                                           float* red4) {
  const float4* ap = (const float4*)a;
  const float4* bp = (const float4*)b;
  float s = 0.f;
  for (int j = threadIdx.x; j < NN / 4; j += 256) {
    float4 x = ap[j], y = bp[j];
    s += x.x * y.x + x.y * y.y + x.z * y.z + x.w * y.w;
  }
  return block_sum(s, red4);
}

// ---------------------------------------------------------------------------
// topk loaders: fill f[48] with this row's values (one wave, 48 vals/lane).
static __device__ inline void load48_bf(const unsigned short* __restrict__ b0,
                                        int parts, int row, int lane,
                                        float* f) {
  const uint4* r0 = (const uint4*)(b0 + (size_t)row * NN);
#pragma unroll
  for (int j = 0; j < 6; ++j) {
    uint4 q = r0[lane + j * 64];
    unsigned uu[4] = {q.x, q.y, q.z, q.w};
#pragma unroll
    for (int e = 0; e < 4; ++e) {
      f[j * 8 + e * 2] = __uint_as_float(uu[e] << 16);
      f[j * 8 + e * 2 + 1] = __uint_as_float(uu[e] & 0xffff0000u);
    }
  }
  for (int p = 1; p < parts; ++p) {
    const uint4* rp = (const uint4*)(b0 + (size_t)p * NN * NN + (size_t)row * NN);
#pragma unroll
    for (int j = 0; j < 6; ++j) {
      uint4 q = rp[lane + j * 64];
      unsigned uu[4] = {q.x, q.y, q.z, q.w};
#pragma unroll
      for (int e = 0; e < 4; ++e) {
        f[j * 8 + e * 2] += __uint_as_float(uu[e] << 16);
        f[j * 8 + e * 2 + 1] += __uint_as_float(uu[e] & 0xffff0000u);
      }
    }
  }
}

static __device__ inline void load48_f32(const float* __restrict__ A, int row,
                                         int lane, float* f) {
  const float4* r0 = (const float4*)(A + (size_t)row * NN);
#pragma unroll
  for (int j = 0; j < 12; ++j) {
    float4 a = r0[lane + j * 64];
    f[j * 4 + 0] = a.x; f[j * 4 + 1] = a.y;
    f[j * 4 + 2] = a.z; f[j * 4 + 3] = a.w;
  }
}

// ---------------------------------------------------------------------------
// select top-64 of the wave's 64x48 values. Radix on bits [30..16] resolved
// TWO bits per step (counts are monotone c3<=c2<=c1, so "largest 2-bit
// pattern with count>=64" == two greedy single-bit steps) with butterfly
// shfl_xor reduces (all lanes end with the total -> no broadcast). Compact
// (idx*DD, val*scale) into out arrays (128 slots; LDS or global).
static __device__ void select_compact(const float* f, int lane, float descale,
                                      int bf, int* __restrict__ outCnt,
                                      int* __restrict__ outIdx,
                                      float* __restrict__ outVal) {
  unsigned bor = 0, band = 0xffffffffu;
#pragma unroll
  for (int r = 0; r < 48; ++r) {
    unsigned k = __float_as_uint(f[r]);
    bor |= k; band &= k;
  }
  for (int off = 32; off; off >>= 1) {
    bor |= (unsigned)__shfl_xor((int)bor, off, 64);
    band &= (unsigned)__shfl_xor((int)band, off, 64);
  }
  unsigned diff = bor ^ band;
  int hi = diff ? (31 - __clz(diff)) : 16;
  if (hi < 16) hi = 16;
  if (hi > 30) hi = 30;
  unsigned t = band & ~((2u << hi) - 1u);

  int b = hi;
  while (b >= 17) {
    unsigned base = 1u << (b - 1);
    unsigned cand1 = t | base;
    unsigned cand2 = t | (base << 1);
    unsigned cand3 = cand2 | base;
    int c1 = 0, c2 = 0, c3 = 0;
#pragma unroll
    for (int r = 0; r < 48; ++r) {
      unsigned k = __float_as_uint(f[r]);
      c1 += (k >= cand1) ? 1 : 0;
      c2 += (k >= cand2) ? 1 : 0;
      c3 += (k >= cand3) ? 1 : 0;
    }
    for (int off = 32; off; off >>= 1) {
      c1 += __shfl_xor(c1, off, 64);
      c2 += __shfl_xor(c2, off, 64);
      c3 += __shfl_xor(c3, off, 64);
    }
    if (c3 >= 64) t = cand3;
    else if (c2 >= 64) t = cand2;
    else if (c1 >= 64) t = cand1;
    b -= 2;
  }
  if (b == 16) {
    unsigned cand = t | (1u << 16);
    int c = 0;
#pragma unroll
    for (int r = 0; r < 48; ++r) c += (__float_as_uint(f[r]) >= cand) ? 1 : 0;
    for (int off = 32; off; off >>= 1) c += __shfl_xor(c, off, 64);
    if (c >= 64) t = cand;
  }

  int basec = 0;
#pragma unroll
  for (int r = 0; r < 48; ++r) {
    bool keep = __float_as_uint(f[r]) >= t;
    unsigned long long m = __ballot(keep);
    if (keep) {
      int pos = basec + __popcll(m & ((1ull << lane) - 1ull));
      if (pos < 128) {
        int col = bf ? ((r >> 3) * 512 + lane * 8 + (r & 7))
                     : ((r >> 2) * 256 + lane * 4 + (r & 3));
        outIdx[pos] = col << 7;  // pre-scaled by DD for gather addressing
        outVal[pos] = f[r] * descale;
      }
    }
    basec += __popcll(m);
  }
  if (lane == 0) *outCnt = basec < 128 ? basec : 128;
}

// ---------------------------------------------------------------------------
// prep: A -> fp8 PACKED (straight + transposed, x2^19) + fused y1/s1 matvec
// partials. blocks [0,2304): 48x48 tiles of 64x64; blocks [2304,2688):
// concat uemb/iemb -> allE (now a dedicated buffer, written here so post1
// sheds its third segment).
__global__ __launch_bounds__(256) void prep(
    const float* __restrict__ A, const float* __restrict__ vu,
    const float* __restrict__ vv, unsigned char* __restrict__ Af8,
    unsigned char* __restrict__ Atf8, float* __restrict__ y1,
    float* __restrict__ s1, const float* __restrict__ uemb,
    const float* __restrict__ iemb, float* __restrict__ allE) {
  __shared__ float sh[64 * 65 + 512];
  const int bid = blockIdx.x;
  const int t = threadIdx.x;
  if (bid >= 2304) {
    int idx = (bid - 2304) * 256 + t;
    int e = idx * 4;
    float4 v = (e < NU * DD) ? *(const float4*)(uemb + e)
                             : *(const float4*)(iemb + (e - NU * DD));
    *(float4*)(allE + e) = v;
    return;
  }
  const int bx = (bid % 48) * 64, by = (bid / 48) * 64;
  const int rr = t >> 4;
  const int c4 = (t & 15) * 4;
  for (int it = 0; it < 4; ++it) {
    int r = rr + it * 16;
    float4 val = *(const float4*)(A + (size_t)(by + r) * NN + bx + c4);
    sh[r * 65 + c4] = val.x; sh[r * 65 + c4 + 1] = val.y;
    sh[r * 65 + c4 + 2] = val.z; sh[r * 65 + c4 + 3] = val.w;
  }
  __syncthreads();
  {
    int row = t >> 2, ch = t & 3;
    const float* sp = &sh[row * 65 + ch * 16];
    uint4 w;
    w.x = pk4_f8(sp[0] * SCALE_A, sp[1] * SCALE_A, sp[2] * SCALE_A,
                 sp[3] * SCALE_A);
    w.y = pk4_f8(sp[4] * SCALE_A, sp[5] * SCALE_A, sp[6] * SCALE_A,
                 sp[7] * SCALE_A);
    w.z = pk4_f8(sp[8] * SCALE_A, sp[9] * SCALE_A, sp[10] * SCALE_A,
                 sp[11] * SCALE_A);
    w.w = pk4_f8(sp[12] * SCALE_A, sp[13] * SCALE_A, sp[14] * SCALE_A,
                 sp[15] * SCALE_A);
    *(uint4*)(Af8 + (size_t)(bx >> 6) * KBLK + (size_t)(by + row) * 64 +
              ch * 16) = w;
  }
  {
    int c = t >> 2, ch = t & 3;
    float v[16];
#pragma unroll
    for (int e = 0; e < 16; ++e) v[e] = sh[(ch * 16 + e) * 65 + c];
    uint4 w;
    w.x = pk4_f8(v[0] * SCALE_A, v[1] * SCALE_A, v[2] * SCALE_A,
                 v[3] * SCALE_A);
    w.y = pk4_f8(v[4] * SCALE_A, v[5] * SCALE_A, v[6] * SCALE_A,
                 v[7] * SCALE_A);
    w.z = pk4_f8(v[8] * SCALE_A, v[9] * SCALE_A, v[10] * SCALE_A,
                 v[11] * SCALE_A);
    w.w = pk4_f8(v[12] * SCALE_A, v[13] * SCALE_A, v[14] * SCALE_A,
                 v[15] * SCALE_A);
    *(uint4*)(Atf8 + (size_t)(by >> 6) * KBLK + (size_t)(bx + c) * 64 +
              ch * 16) = w;
  }
  const int q = t >> 6;
  const int l = t & 63;
  float sy = 0.f, ss_ = 0.f;
  for (int i = 0; i < 16; ++i) {
    int c = q * 16 + i;
    sy += sh[l * 65 + c] * vv[bx + c];
    ss_ += vu[by + c] * sh[c * 65 + l];
  }
  float* red = sh + 64 * 65;
  red[q * 64 + l] = sy;
  red[256 + q * 64 + l] = ss_;
  __syncthreads();
  if (t < 64) {
    float v4 = red[t] + red[64 + t] + red[128 + t] + red[192 + t];
    atomAddF(&y1[by + t], v4);
  } else if (t < 128) {
    int cc = t - 64;
    float v4 = red[256 + cc] + red[256 + 64 + cc] + red[256 + 128 + cc] +
               red[256 + 192 + cc];
    atomAddF(&s1[bx + cc], v4);
  }
}

// ---------------------------------------------------------------------------
// gemm_f8 v8: 3-buffer LDS pipeline with COUNTED vmcnt (T3/T4-minimum).
// v7's __syncthreads() drained vmcnt(0) every K-step -> the prefetch never
// stayed in flight (MfmaUtil 24%). v8: raw s_barrier + inline-asm
// s_waitcnt vmcnt(4) (own 4 stage-kt loads done; stages kt+1, kt+2 remain
// in flight ACROSS the barrier). One barrier per K-step.
// Race safety: STAGE(kt+2) overwrites buf[(kt-1)%3]; all waves' reads of
// that buffer completed before their MFMA issue at iter kt-1, which
// precedes barrier(kt) in program order; STAGE is issued after barrier(kt).
// sched_barrier(0) after the barrier and at loop end pins the region
// (rule #18: MFMA/loads can otherwise cross inline-asm waitcnt).
#define MFMA4(A0, A1, B0, B1)                                          \
  acc[0][0] = __builtin_amdgcn_mfma_scale_f32_32x32x64_f8f6f4(         \
      A0, B0, acc[0][0], 0, 0, 0, 127, 0, 127);                        \
  acc[0][1] = __builtin_amdgcn_mfma_scale_f32_32x32x64_f8f6f4(         \
      A0, B1, acc[0][1], 0, 0, 0, 127, 0, 127);                        \
  acc[1][0] = __builtin_amdgcn_mfma_scale_f32_32x32x64_f8f6f4(         \
      A1, B0, acc[1][0], 0, 0, 0, 127, 0, 127);                        \
  acc[1][1] = __builtin_amdgcn_mfma_scale_f32_32x32x64_f8f6f4(         \
      A1, B1, acc[1][1], 0, 0, 0, 127, 0, 127);

static __device__ inline i32x8 ldfragL(const char* p) {
  i32x4 lo = *(const i32x4*)p;
  i32x4 hi = *(const i32x4*)(p + 1024);
  return (i32x8){lo.x, lo.y, lo.z, lo.w, hi.x, hi.y, hi.z, hi.w};
}

__global__ __launch_bounds__(256) void gemm_f8(
    const unsigned char* __restrict__ Ag,
    const unsigned char* __restrict__ Btg,
    unsigned short* __restrict__ Cg) {
  __shared__ char smem[3][16384];
  // XCD column-ownership swizzle (bijective over 576 = 8 XCD x 3 col x 24 row)
  const int wg = blockIdx.x;
  const int xcd = wg & 7;
  const int idx = wg >> 3;                 // 0..71
  const int bxi = xcd * 3 + (idx % 3);     // column panel
  const int byi = idx / 3;                 // row panel
  const int rowBase = byi * 128, colBase = bxi * 128;

  const int t = threadIdx.x;
  const int w = t >> 6, l = t & 63;
  const int wr = w >> 1, wc = w & 1;
  const int r32 = l & 31, hh = l >> 5;

  f32x16 acc[2][2];
  for (int i = 0; i < 2; ++i)
    for (int j = 0; j < 2; ++j)
      for (int e = 0; e < 16; ++e) acc[i][j][e] = 0.f;

  const unsigned char* aT = Ag + (size_t)rowBase * 64;
  const unsigned char* bT = Btg + (size_t)colBase * 64;
  // per-lane source offset within a chunk's 32-row group
  const int laneOff = r32 * 64 + hh * 32;

#define STAGE(kt, b)                                                        \
  {                                                                         \
    const size_t kOff = (size_t)(kt) * KBLK;                                \
    _Pragma("unroll") for (int r_ = 0; r_ < 4; ++r_) {                      \
      int q_ = r_ * 4 + w;                                                  \
      int s_ = (q_ >> 1) & 3, h_ = q_ & 1;                                  \
      const unsigned char* g_ = ((q_ < 8) ? aT : bT) + kOff +               \
                                (size_t)(s_ * 32) * 64 + laneOff + h_ * 16; \
      __builtin_amdgcn_global_load_lds(                                     \
          (const __attribute__((address_space(1))) unsigned*)g_,            \
          (__attribute__((address_space(3))) unsigned*)(smem[b] +           \
                                                        q_ * 1024),         \
          16, 0, 0);                                                        \
    }                                                                       \
  }

  const int nt = NN / 64;  // 48
  STAGE(0, 0);
  STAGE(1, 1);
  for (int kt = 0; kt < nt; ++kt) {
    // wait own stage-kt loads (4); stages kt+1/kt+2 stay in flight
    if (kt < nt - 1) {
      asm volatile("s_waitcnt vmcnt(4)" ::: "memory");
    } else {
      asm volatile("s_waitcnt vmcnt(0)" ::: "memory");
    }
    __builtin_amdgcn_s_barrier();
    __builtin_amdgcn_sched_barrier(0);
    const char* sb = smem[kt % 3];
    i32x8 a0 = ldfragL(sb + (wr * 2 + 0) * 2048 + l * 16);
    i32x8 a1 = ldfragL(sb + (wr * 2 + 1) * 2048 + l * 16);
    i32x8 b0 = ldfragL(sb + 8192 + (wc * 2 + 0) * 2048 + l * 16);
    i32x8 b1 = ldfragL(sb + 8192 + (wc * 2 + 1) * 2048 + l * 16);
    if (kt + 2 < nt) STAGE(kt + 2, (kt + 2) % 3);
    __builtin_amdgcn_s_setprio(1);
    MFMA4(a0, a1, b0, b1);
    __builtin_amdgcn_s_setprio(0);
    __builtin_amdgcn_sched_barrier(0);
  }
#undef STAGE

  // C/D 32x32 layout: col = lane&31, row = (reg&3) + 8*(reg>>2) + 4*(lane>>5)
  for (int i = 0; i < 2; ++i) {
    int rb = rowBase + wr * 64 + i * 32 + 4 * hh;
    for (int j = 0; j < 2; ++j) {
      int cc = colBase + wc * 64 + j * 32 + r32;
      for (int reg = 0; reg < 16; ++reg) {
        int rr = rb + (reg & 3) + 8 * (reg >> 2);
        Cg[(size_t)rr * NN + cc] = bf16bits(acc[i][j][reg]);
      }
    }
  }
}

// ---------------------------------------------------------------------------
// post1: [0,768)     topk(A2 bf16) + packed fp8 cast -> A2f8
//        [768,1536)  tvec = A.y1 (one wave per row)
__global__ __launch_bounds__(256) void post1(
    const unsigned short* __restrict__ C, int parts,
    const float* __restrict__ A, const float* __restrict__ y1,
    unsigned char* __restrict__ A2f8, int* __restrict__ cnts1,
    int* __restrict__ tIdx1, float* __restrict__ tVal1,
    float* __restrict__ tvec) {
  const int bid = blockIdx.x;
  const int t = threadIdx.x;
  if (bid < 768) {
    int row = bid * 4 + (t >> 6);
    int lane = t & 63;
    float f[48];
    load48_bf(C, parts, row, lane, f);
    // fused packed fp8 cast: f[j*8+e] = col k0+e, k0=(j*64+lane)*8
#pragma unroll
    for (int j = 0; j < 6; ++j) {
      uint2 w;
      w.x = pk4_f8(f[j * 8 + 0] * F8SCALE2, f[j * 8 + 1] * F8SCALE2,
                   f[j * 8 + 2] * F8SCALE2, f[j * 8 + 3] * F8SCALE2);
      w.y = pk4_f8(f[j * 8 + 4] * F8SCALE2, f[j * 8 + 5] * F8SCALE2,
                   f[j * 8 + 6] * F8SCALE2, f[j * 8 + 7] * F8SCALE2);
      size_t addr = (size_t)(j * 8 + (lane >> 3)) * KBLK +
                    (size_t)row * 64 + (lane & 7) * 8;
      *(uint2*)(A2f8 + addr) = w;
    }
    select_compact(f, lane, DESCALE38, 1, &cnts1[row],
                   tIdx1 + (size_t)row * 128, tVal1 + (size_t)row * 128);
  } else {
    int row = (bid - 768) * 4 + (t >> 6);
    int lane = t & 63;
    const float4* rp = (const float4*)(A + (size_t)row * NN);
    const float4* yp = (const float4*)y1;
    float s = 0.f;
#pragma unroll
    for (int j = 0; j < 12; ++j) {
      float4 a = rp[lane + j * 64];
      float4 y = yp[lane + j * 64];
      s += a.x * y.x + a.y * y.y + a.z * y.z + a.w * y.w;
    }
    for (int off = 32; off; off >>= 1) s += __shfl_down(s, off, 64);
    if (lane == 0) tvec[row] = s;
  }
}

// ---------------------------------------------------------------------------
// sel02: phase-homogeneous select kernel (one select per wave, dense waves).
//   bid < 1536, even: layer-2 lists from C (A3 bf16) -> global
//   bid < 1536, odd:  layer-0 lists from A (fp32)    -> global
//   bid == 1536:      post2 fold (w0..w3 -> wacc) — removes a serial
//                     single-block launch.
__global__ __launch_bounds__(256) void sel02(
    const unsigned short* __restrict__ C, int parts,
    const float* __restrict__ A, int* __restrict__ cnt0,
    int* __restrict__ idx0, float* __restrict__ val0,
    int* __restrict__ cnt2, int* __restrict__ idx2,
    float* __restrict__ val2, const float* __restrict__ vu,
    const float* __restrict__ vv, const float* __restrict__ y1,
    const float* __restrict__ s1, const float* __restrict__ tvec,
    float* __restrict__ wacc) {
  __shared__ float red4[4];
  const int bid = blockIdx.x;
  const int t = threadIdx.x;
  if (bid == 1536) {
    float w0 = row_dot_f32(vu, vv, red4);  __syncthreads();
    float w1 = row_dot_f32(vu, y1, red4);  __syncthreads();
    float w2 = row_dot_f32(s1, y1, red4);  __syncthreads();
    float w3 = row_dot_f32(s1, tvec, red4);
    if (t == 0) { wacc[0] = w0; wacc[1] = w1; wacc[2] = w2; wacc[3] = w3; }
    return;
  }
  const int w = t >> 6, lane = t & 63;
  const int row = (bid >> 1) * 4 + w;
  float f[48];
  if ((bid & 1) == 0) {
    load48_bf(C, parts, row, lane, f);
    select_compact(f, lane, DESCALE38, 1, &cnt2[row],
                   idx2 + (size_t)row * 128, val2 + (size_t)row * 128);
  } else {
    load48_f32(A, row, lane, f);
    select_compact(f, lane, 1.0f, 0, &cnt0[row],
                   idx0 + (size_t)row * 128, val0 + (size_t)row * 128);
  }
}

// ---------------------------------------------------------------------------
// gather_light: pure gather, one wave per row (768 blocks x 256 thr).
// All three layer lists concatenated into one LDS run with the attention
// weights folded into the values at staging; float2 gather (64 lanes cover
// the 128 dims), 8 independent loads in flight, no __syncthreads.
__global__ __launch_bounds__(256) void gather_light(
    const float* __restrict__ allE, const float* __restrict__ uemb0,
    const float* __restrict__ iemb0, const float* __restrict__ wacc,
    const int* __restrict__ cnt0, const int* __restrict__ idx0,
    const float* __restrict__ val0, const int* __restrict__ cnts1,
    const int* __restrict__ tIdx1, const float* __restrict__ tVal1,
    const int* __restrict__ cnt2, const int* __restrict__ idx2,
    const float* __restrict__ val2, float* __restrict__ lightOut) {
  __shared__ int li[4][384];
  __shared__ float lv[4][384];
  const int t = threadIdx.x;
  const int w = t >> 6, lane = t & 63;
  const int row = blockIdx.x * 4 + w;

  float w0 = wacc[0], w1 = wacc[1], w2 = wacc[2], w3 = wacc[3];
  float ss = w0 + w1 + w2 + w3;
  w0 /= ss; w1 /= ss; w2 /= ss; w3 /= ss;
  float m = fmaxf(fmaxf(w0, w1), fmaxf(w2, w3));
  float ex0 = expf(w0 - m), ex1 = expf(w1 - m), ex2 = expf(w2 - m),
        ex3 = expf(w3 - m);
  float se = ex0 + ex1 + ex2 + ex3;
  float aw0 = ex0 / se, aw1 = ex1 / se, aw2 = ex2 / se, aw3 = ex3 / se;
  float aw4 = GAMMA_F * (aw1 + aw2 + aw3);

  const int c0 = cnt0[row], c1 = cnts1[row], c2 = cnt2[row];
  const int p0 = (c0 + 7) & ~7, p1 = (c1 + 7) & ~7, p2 = (c2 + 7) & ~7;
  int* Li = li[w];
  float* Lv = lv[w];
  const size_t rb = (size_t)row * 128;
  for (int k = lane; k < p0; k += 64) {
    bool in = k < c0;
    Li[k] = in ? idx0[rb + k] : 0;
    Lv[k] = in ? aw1 * val0[rb + k] : 0.f;
  }
  for (int k = lane; k < p1; k += 64) {
    bool in = k < c1;
    Li[p0 + k] = in ? tIdx1[rb + k] : 0;
    Lv[p0 + k] = in ? aw2 * tVal1[rb + k] : 0.f;
  }
  for (int k = lane; k < p2; k += 64) {
    bool in = k < c2;
    Li[p0 + p1 + k] = in ? idx2[rb + k] : 0;
    Lv[p0 + p1 + k] = in ? aw3 * val2[rb + k] : 0.f;
  }
  // same-wave produce->consume through LDS: compiler orders via lgkmcnt.

  const int ct = p0 + p1 + p2;
  const float2* E2 = (const float2*)allE;
  float ax = 0.f, ay = 0.f, bx_ = 0.f, by_ = 0.f;
  for (int k = 0; k < ct; k += 8) {
    int i0 = Li[k + 0], i1 = Li[k + 1], i2 = Li[k + 2], i3 = Li[k + 3];
    int i4 = Li[k + 4], i5 = Li[k + 5], i6 = Li[k + 6], i7 = Li[k + 7];
    float v0 = Lv[k + 0], v1 = Lv[k + 1], v2 = Lv[k + 2], v3 = Lv[k + 3];
    float v4 = Lv[k + 4], v5 = Lv[k + 5], v6 = Lv[k + 6], v7 = Lv[k + 7];
    float2 g0 = E2[(i0 >> 1) + lane];
    float2 g1 = E2[(i1 >> 1) + lane];
    float2 g2 = E2[(i2 >> 1) + lane];
    float2 g3 = E2[(i3 >> 1) + lane];
    float2 g4 = E2[(i4 >> 1) + lane];
    float2 g5 = E2[(i5 >> 1) + lane];
    float2 g6 = E2[(i6 >> 1) + lane];
    float2 g7 = E2[(i7 >> 1) + lane];
    ax += v0 * g0.x; ay += v0 * g0.y;
    bx_ += v1 * g1.x; by_ += v1 * g1.y;
    ax += v2 * g2.x; ay += v2 * g2.y;
    bx_ += v3 * g3.x; by_ += v3 * g3.y;
    ax += v4 * g4.x; ay += v4 * g4.y;
    bx_ += v5 * g5.x; by_ += v5 * g5.y;
    ax += v6 * g6.x; ay += v6 * g6.y;
    bx_ += v7 * g7.x; by_ += v7 * g7.y;
  }
  float2 sE = E2[((size_t)row << 6) + lane];
  float2 e0 = (row < NU)
                  ? ((const float2*)uemb0)[(size_t)row * 64 + lane]
                  : ((const float2*)iemb0)[(size_t)(row - NU) * 64 + lane];
  float ox = (ax + bx_) + aw0 * sE.x + aw4 * e0.x;
  float oy = (ay + by_) + aw0 * sE.y + aw4 * e0.y;
  float2 o; o.x = ox; o.y = oy;
  ((float2*)lightOut)[(size_t)row * 64 + lane] = o;
}

__global__ __launch_bounds__(256) void out_dot(const int* __restrict__ users,
                                               const int* __restrict__ items,
                                               const float* __restrict__ lightOut,
                                               float* __restrict__ out) {
  int b = blockIdx.x * 4 + (threadIdx.x >> 6);
  int lane = threadIdx.x & 63;
  const float* up = lightOut + (size_t)users[b] * DD;
  const float* ip = lightOut + (size_t)(NU + items[b]) * DD;
  float s = up[lane] * ip[lane] + up[lane + 64] * ip[lane + 64];
  for (int off = 32; off; off >>= 1) s += __shfl_down(s, off, 64);
  if (lane == 0) out[b] = s;
}

// ---------------------------------------------------------------------------
extern "C" void kernel_launch(void* const* d_in, const int* in_sizes, int n_in,
                              void* d_out, int out_size, void* d_ws,
                              size_t ws_size, hipStream_t stream) {
  const int* users = (const int*)d_in[0];
  const int* items = (const int*)d_in[1];
  const float* A = (const float*)d_in[2];
  const float* uemb = (const float*)d_in[3];
  const float* iemb = (const float*)d_in[4];
  const float* uemb0 = (const float*)d_in[5];
  const float* iemb0 = (const float*)d_in[6];
  const float* vu = (const float*)d_in[7];
  const float* vv = (const float*)d_in[8];
  float* out = (float*)d_out;

  char* ws = (char*)d_ws;
  size_t off = 0;
  auto alloc = [&](size_t bytes) -> void* {
    void* p = ws + off;
    off += (bytes + 255) & ~(size_t)255;
    return p;
  };
  unsigned char* Af8 = (unsigned char*)alloc((size_t)NN * NN);
  unsigned char* Atf8 = (unsigned char*)alloc((size_t)NN * NN);
  unsigned char* A2f8 = (unsigned char*)alloc((size_t)NN * NN);
  float* y1 = (float*)alloc((size_t)NN * 4);   // contiguous with s1
  float* s1 = (float*)alloc((size_t)NN * 4);
  float* tvec = (float*)alloc((size_t)NN * 4);
  float* wacc = (float*)alloc(256);
  int* cnts1 = (int*)alloc((size_t)NN * 4);
  int* tIdx1 = (int*)alloc((size_t)NN * 128 * 4);
  float* tVal1 = (float*)alloc((size_t)NN * 128 * 4);
  float* lightOut = (float*)alloc((size_t)NN * DD * 4);
  int* cnt0 = (int*)alloc((size_t)NN * 4);
  int* cnt2 = (int*)alloc((size_t)NN * 4);
  float* allE = (float*)alloc((size_t)NN * DD * 4);  // dedicated (no alias)

  // layer-0/2 lists (4 x 1.5 MB) alias Atf8 (9.4 MB): Atf8 is dead after
  // gemm#2 (step 5); sel02 (step 6) writes, gather (step 8) reads.
  const size_t LSTB = (size_t)NN * 128 * 4;
  int* idx0 = (int*)(Atf8);
  float* val0 = (float*)(Atf8 + LSTB);
  int* idx2 = (int*)(Atf8 + 2 * LSTB);
  float* val2 = (float*)(Atf8 + 3 * LSTB);

  // single-part bf16 C (the pipelined GEMM needs no K-split; halves C I/O)
  unsigned short* C = (unsigned short*)alloc((size_t)NN * NN * 2);

  // 1) zero y1/s1 (contiguous 2*NN floats)
  hipMemsetAsync(y1, 0, (size_t)2 * NN * 4, stream);
  // 2) prep: A -> packed fp8 (straight+transposed) + y1/s1 | emb concat
  prep<<<2688, 256, 0, stream>>>(A, vu, vv, Af8, Atf8, y1, s1, uemb, iemb,
                                 allE);
  // 3) A2 = A*A (3-buffer counted-vmcnt pipelined MX fp8 MFMA)
  gemm_f8<<<576, 256, 0, stream>>>(Af8, Atf8, C);
  // 4) post1: topk(A2)+packed fp8 cast | tvec = A.y1
  post1<<<1536, 256, 0, stream>>>(C, 1, A, y1, A2f8, cnts1, tIdx1, tVal1,
                                  tvec);
  // 5) A3 = A2*A (overwrite C)
  gemm_f8<<<576, 256, 0, stream>>>(A2f8, Atf8, C);
  // 6) sel02: layer-0 (A) + layer-2 (A3) top-64 lists | post2 fold (bid 1536)
  sel02<<<1537, 256, 0, stream>>>(C, 1, A, cnt0, idx0, val0, cnt2, idx2,
                                  val2, vu, vv, y1, s1, tvec, wacc);
  // 7) gather_light: pure float2 gather, one wave per row
  gather_light<<<768, 256, 0, stream>>>(allE, uemb0, iemb0, wacc, cnt0, idx0,
                                        val0, cnts1, tIdx1, tVal1, cnt2, idx2,
                                        val2, lightOut);
  // 8) gather dots
  out_dot<<<BB / 4, 256, 0, stream>>>(users, items, lightOut, out);
}

// Round 8
// 239.870 us; speedup vs baseline: 1.3232x; 1.0799x over previous
//
#include <hip/hip_runtime.h>
#include <hip/hip_fp8.h>
#include <math.h>

#define NN 3072
#define NU 1024
#define NI 2048
#define DD 128
#define BB 8192
#define GAMMA_F 0.2f

#define SCALE_A 524288.0f                // 2^19
#define F8SCALE2 1.9073486328125e-06f    // 2^-19  (C*2^38 -> A2*2^19 for fp8)
#define DESCALE38 3.637978807091713e-12f // 2^-38  (C -> true A^k values)

// packed fp8 layout: [k/64][row][k%64]; one k-block = NN rows x 64 B
#define KBLK ((size_t)NN * 64)

typedef __attribute__((ext_vector_type(4))) float f32x4;
typedef __attribute__((ext_vector_type(16))) float f32x16;
typedef __attribute__((ext_vector_type(4))) int i32x4;
typedef __attribute__((ext_vector_type(8))) int i32x8;

static __device__ inline unsigned short bf16bits(float x) {
  union { unsigned u; float f; } cv;
  cv.f = x;
  unsigned r = cv.u + 0x7fff + ((cv.u >> 16) & 1);  // RNE
  return (unsigned short)(r >> 16);
}

// pack 4 floats -> 4 fp8 e4m3 (OCP) bytes
static __device__ inline unsigned pk4_f8(float a, float b, float c, float d) {
#if defined(__has_builtin)
#if __has_builtin(__builtin_amdgcn_cvt_pk_fp8_f32)
  int p = __builtin_amdgcn_cvt_pk_fp8_f32(a, b, 0, false);
  p = __builtin_amdgcn_cvt_pk_fp8_f32(c, d, p, true);
  return (unsigned)p;
#else
  return (unsigned)__hip_fp8_e4m3(a).__x | ((unsigned)__hip_fp8_e4m3(b).__x << 8) |
         ((unsigned)__hip_fp8_e4m3(c).__x << 16) |
         ((unsigned)__hip_fp8_e4m3(d).__x << 24);
#endif
#else
  return (unsigned)__hip_fp8_e4m3(a).__x | ((unsigned)__hip_fp8_e4m3(b).__x << 8) |
         ((unsigned)__hip_fp8_e4m3(c).__x << 16) |
         ((unsigned)__hip_fp8_e4m3(d).__x << 24);
#endif
}

static __device__ inline void atomAddF(float* p, float v) {
#if defined(__has_builtin)
#if __has_builtin(__builtin_amdgcn_global_atomic_fadd_f32)
  __builtin_amdgcn_global_atomic_fadd_f32(
      (__attribute__((address_space(1))) float*)p, v);
#else
  unsafeAtomicAdd(p, v);
#endif
#else
  unsafeAtomicAdd(p, v);
#endif
}

static __device__ inline float block_sum(float s, float* red4) {
  int tid = threadIdx.x;
  for (int off = 32; off; off >>= 1) s += __shfl_down(s, off, 64);
  if ((tid & 63) == 0) red4[tid >> 6] = s;
  __syncthreads();
  return red4[0] + red4[1] + red4[2] + red4[3];
}

static __device__ inline float row_dot_f32(const float* __restrict__ a,
                                           const float* __restrict__ b,
                                           float* red4) {
  const float4* ap = (const float4*)a;
  const float4* bp = (const float4*)b;
  float s = 0.f;
  for (int j = threadIdx.x; j < NN / 4; j += 256) {
    float4 x = ap[j], y = bp[j];
    s += x.x * y.x + x.y * y.y + x.z * y.z + x.w * y.w;
  }
  return block_sum(s, red4);
}

// ---------------------------------------------------------------------------
// topk loaders: fill f[48] with this row's values (one wave, 48 vals/lane).
static __device__ inline void load48_bf(const unsigned short* __restrict__ b0,
                                        int parts, int row, int lane,
                                        float* f) {
  const uint4* r0 = (const uint4*)(b0 + (size_t)row * NN);
#pragma unroll
  for (int j = 0; j < 6; ++j) {
    uint4 q = r0[lane + j * 64];
    unsigned uu[4] = {q.x, q.y, q.z, q.w};
#pragma unroll
    for (int e = 0; e < 4; ++e) {
      f[j * 8 + e * 2] = __uint_as_float(uu[e] << 16);
      f[j * 8 + e * 2 + 1] = __uint_as_float(uu[e] & 0xffff0000u);
    }
  }
  for (int p = 1; p < parts; ++p) {
    const uint4* rp = (const uint4*)(b0 + (size_t)p * NN * NN + (size_t)row * NN);
#pragma unroll
    for (int j = 0; j < 6; ++j) {
      uint4 q = rp[lane + j * 64];
      unsigned uu[4] = {q.x, q.y, q.z, q.w};
#pragma unroll
      for (int e = 0; e < 4; ++e) {
        f[j * 8 + e * 2] += __uint_as_float(uu[e] << 16);
        f[j * 8 + e * 2 + 1] += __uint_as_float(uu[e] & 0xffff0000u);
      }
    }
  }
}

static __device__ inline void load48_f32(const float* __restrict__ A, int row,
                                         int lane, float* f) {
  const float4* r0 = (const float4*)(A + (size_t)row * NN);
#pragma unroll
  for (int j = 0; j < 12; ++j) {
    float4 a = r0[lane + j * 64];
    f[j * 4 + 0] = a.x; f[j * 4 + 1] = a.y;
    f[j * 4 + 2] = a.z; f[j * 4 + 3] = a.w;
  }
}

// ---------------------------------------------------------------------------
// select top-64 of the wave's 64x48 values. Radix on bits [30..16] resolved
// TWO bits per step (counts are monotone c3<=c2<=c1, so "largest 2-bit
// pattern with count>=64" == two greedy single-bit steps) with butterfly
// shfl_xor reduces (all lanes end with the total -> no broadcast). Compact
// (idx*DD, val*scale) into out arrays (128 slots; LDS or global).
static __device__ void select_compact(const float* f, int lane, float descale,
                                      int bf, int* __restrict__ outCnt,
                                      int* __restrict__ outIdx,
                                      float* __restrict__ outVal) {
  unsigned bor = 0, band = 0xffffffffu;
#pragma unroll
  for (int r = 0; r < 48; ++r) {
    unsigned k = __float_as_uint(f[r]);
    bor |= k; band &= k;
  }
  for (int off = 32; off; off >>= 1) {
    bor |= (unsigned)__shfl_xor((int)bor, off, 64);
    band &= (unsigned)__shfl_xor((int)band, off, 64);
  }
  unsigned diff = bor ^ band;
  int hi = diff ? (31 - __clz(diff)) : 16;
  if (hi < 16) hi = 16;
  if (hi > 30) hi = 30;
  unsigned t = band & ~((2u << hi) - 1u);

  int b = hi;
  while (b >= 17) {
    unsigned base = 1u << (b - 1);
    unsigned cand1 = t | base;
    unsigned cand2 = t | (base << 1);
    unsigned cand3 = cand2 | base;
    int c1 = 0, c2 = 0, c3 = 0;
#pragma unroll
    for (int r = 0; r < 48; ++r) {
      unsigned k = __float_as_uint(f[r]);
      c1 += (k >= cand1) ? 1 : 0;
      c2 += (k >= cand2) ? 1 : 0;
      c3 += (k >= cand3) ? 1 : 0;
    }
    for (int off = 32; off; off >>= 1) {
      c1 += __shfl_xor(c1, off, 64);
      c2 += __shfl_xor(c2, off, 64);
      c3 += __shfl_xor(c3, off, 64);
    }
    if (c3 >= 64) t = cand3;
    else if (c2 >= 64) t = cand2;
    else if (c1 >= 64) t = cand1;
    b -= 2;
  }
  if (b == 16) {
    unsigned cand = t | (1u << 16);
    int c = 0;
#pragma unroll
    for (int r = 0; r < 48; ++r) c += (__float_as_uint(f[r]) >= cand) ? 1 : 0;
    for (int off = 32; off; off >>= 1) c += __shfl_xor(c, off, 64);
    if (c >= 64) t = cand;
  }

  int basec = 0;
#pragma unroll
  for (int r = 0; r < 48; ++r) {
    bool keep = __float_as_uint(f[r]) >= t;
    unsigned long long m = __ballot(keep);
    if (keep) {
      int pos = basec + __popcll(m & ((1ull << lane) - 1ull));
      if (pos < 128) {
        int col = bf ? ((r >> 3) * 512 + lane * 8 + (r & 7))
                     : ((r >> 2) * 256 + lane * 4 + (r & 3));
        outIdx[pos] = col << 7;  // pre-scaled by DD for gather addressing
        outVal[pos] = f[r] * descale;
      }
    }
    basec += __popcll(m);
  }
  if (lane == 0) *outCnt = basec < 128 ? basec : 128;
}

// ---------------------------------------------------------------------------
// prep: A -> fp8 PACKED (straight + transposed, x2^19) + fused y1/s1 matvec
// partials. blocks [0,2304): 48x48 tiles of 64x64; blocks [2304,2688):
// concat uemb/iemb -> allE.
__global__ __launch_bounds__(256) void prep(
    const float* __restrict__ A, const float* __restrict__ vu,
    const float* __restrict__ vv, unsigned char* __restrict__ Af8,
    unsigned char* __restrict__ Atf8, float* __restrict__ y1,
    float* __restrict__ s1, const float* __restrict__ uemb,
    const float* __restrict__ iemb, float* __restrict__ allE) {
  __shared__ float sh[64 * 65 + 512];
  const int bid = blockIdx.x;
  const int t = threadIdx.x;
  if (bid >= 2304) {
    int idx = (bid - 2304) * 256 + t;
    int e = idx * 4;
    float4 v = (e < NU * DD) ? *(const float4*)(uemb + e)
                             : *(const float4*)(iemb + (e - NU * DD));
    *(float4*)(allE + e) = v;
    return;
  }
  const int bx = (bid % 48) * 64, by = (bid / 48) * 64;
  const int rr = t >> 4;
  const int c4 = (t & 15) * 4;
  for (int it = 0; it < 4; ++it) {
    int r = rr + it * 16;
    float4 val = *(const float4*)(A + (size_t)(by + r) * NN + bx + c4);
    sh[r * 65 + c4] = val.x; sh[r * 65 + c4 + 1] = val.y;
    sh[r * 65 + c4 + 2] = val.z; sh[r * 65 + c4 + 3] = val.w;
  }
  __syncthreads();
  {
    int row = t >> 2, ch = t & 3;
    const float* sp = &sh[row * 65 + ch * 16];
    uint4 w;
    w.x = pk4_f8(sp[0] * SCALE_A, sp[1] * SCALE_A, sp[2] * SCALE_A,
                 sp[3] * SCALE_A);
    w.y = pk4_f8(sp[4] * SCALE_A, sp[5] * SCALE_A, sp[6] * SCALE_A,
                 sp[7] * SCALE_A);
    w.z = pk4_f8(sp[8] * SCALE_A, sp[9] * SCALE_A, sp[10] * SCALE_A,
                 sp[11] * SCALE_A);
    w.w = pk4_f8(sp[12] * SCALE_A, sp[13] * SCALE_A, sp[14] * SCALE_A,
                 sp[15] * SCALE_A);
    *(uint4*)(Af8 + (size_t)(bx >> 6) * KBLK + (size_t)(by + row) * 64 +
              ch * 16) = w;
  }
  {
    int c = t >> 2, ch = t & 3;
    float v[16];
#pragma unroll
    for (int e = 0; e < 16; ++e) v[e] = sh[(ch * 16 + e) * 65 + c];
    uint4 w;
    w.x = pk4_f8(v[0] * SCALE_A, v[1] * SCALE_A, v[2] * SCALE_A,
                 v[3] * SCALE_A);
    w.y = pk4_f8(v[4] * SCALE_A, v[5] * SCALE_A, v[6] * SCALE_A,
                 v[7] * SCALE_A);
    w.z = pk4_f8(v[8] * SCALE_A, v[9] * SCALE_A, v[10] * SCALE_A,
                 v[11] * SCALE_A);
    w.w = pk4_f8(v[12] * SCALE_A, v[13] * SCALE_A, v[14] * SCALE_A,
                 v[15] * SCALE_A);
    *(uint4*)(Atf8 + (size_t)(by >> 6) * KBLK + (size_t)(bx + c) * 64 +
              ch * 16) = w;
  }
  const int q = t >> 6;
  const int l = t & 63;
  float sy = 0.f, ss_ = 0.f;
  for (int i = 0; i < 16; ++i) {
    int c = q * 16 + i;
    sy += sh[l * 65 + c] * vv[bx + c];
    ss_ += vu[by + c] * sh[c * 65 + l];
  }
  float* red = sh + 64 * 65;
  red[q * 64 + l] = sy;
  red[256 + q * 64 + l] = ss_;
  __syncthreads();
  if (t < 64) {
    float v4 = red[t] + red[64 + t] + red[128 + t] + red[192 + t];
    atomAddF(&y1[by + t], v4);
  } else if (t < 128) {
    int cc = t - 64;
    float v4 = red[256 + cc] + red[256 + 64 + cc] + red[256 + 128 + cc] +
               red[256 + 192 + cc];
    atomAddF(&s1[bx + cc], v4);
  }
}

// ---------------------------------------------------------------------------
// gemm_f8 v9: 192x192 block tile, 4 waves of 96x96 (3x3 MFMA tiles).
// v8 post-mortem: counted vmcnt was flat because the kernel is LDS-READ-
// BANDWIDTH-bound — the 2x2 wave tile reads 2 KB LDS per MFMA (each frag
// used 2x). 3x3 reads 1.33 KB/MFMA (frags used 3x): per-CU LDS reads/step
// 48 KB (578cy @85B/cy) < MFMA 620cy -> MFMA-dominant. Grid (3072/192)^2 =
// 256 = exactly 1 block/CU (kills v8's 2.25-round tail).
// Same verified chunk(s,h)<->lane*16 LDS mapping (6 row-subtiles now),
// same 3-buffer counted-vmcnt pipeline (24 KB/buffer, vmcnt(6)).
static __device__ inline i32x8 ldfragL(const char* p) {
  i32x4 lo = *(const i32x4*)p;
  i32x4 hi = *(const i32x4*)(p + 1024);
  return (i32x8){lo.x, lo.y, lo.z, lo.w, hi.x, hi.y, hi.z, hi.w};
}

__global__ __launch_bounds__(256) void gemm_f8(
    const unsigned char* __restrict__ Ag,
    const unsigned char* __restrict__ Btg,
    unsigned short* __restrict__ Cg) {
  __shared__ char smem[3][24576];
  // grid 256 = 16x16 panels of 192; each XCD owns 2 column panels (B panel
  // working set 2 x 576 KB = 1.15 MB -> L2-resident for the whole GEMM).
  const int wg = blockIdx.x;
  const int xcd = wg & 7;
  const int idx = wg >> 3;             // 0..31
  const int bxi = xcd * 2 + (idx & 1); // column panel 0..15
  const int byi = idx >> 1;            // row panel    0..15
  const int rowBase = byi * 192, colBase = bxi * 192;

  const int t = threadIdx.x;
  const int w = t >> 6, l = t & 63;
  const int wr = w >> 1, wc = w & 1;
  const int r32 = l & 31, hh = l >> 5;

  f32x16 acc[3][3];
#pragma unroll
  for (int i = 0; i < 3; ++i)
#pragma unroll
    for (int j = 0; j < 3; ++j)
#pragma unroll
      for (int e = 0; e < 16; ++e) acc[i][j][e] = 0.f;

  const unsigned char* aT = Ag + (size_t)rowBase * 64;
  const unsigned char* bT = Btg + (size_t)colBase * 64;
  const int laneOff = r32 * 64 + hh * 32;

  // 24 chunks x 1KB per buffer: q<12 = A (6 row-subtiles x 2 halves),
  // q>=12 = B. Chunk (s,h) at lane slot l*16 holds global bytes
  // {row = s*32 + (l&31), byte = (l>>5)*32 + h*16} — the exact MFMA
  // operand bytes for lane l (verified mapping from v7).
#define STAGE(kt, b)                                                        \
  {                                                                         \
    const size_t kOff = (size_t)(kt) * KBLK;                                \
    _Pragma("unroll") for (int r_ = 0; r_ < 6; ++r_) {                      \
      int q_ = r_ * 4 + w;                                                  \
      int qq_ = q_ < 12 ? q_ : q_ - 12;                                     \
      int s_ = qq_ >> 1, h_ = qq_ & 1;                                      \
      const unsigned char* g_ = ((q_ < 12) ? aT : bT) + kOff +              \
                                (size_t)(s_ * 32) * 64 + laneOff + h_ * 16; \
      __builtin_amdgcn_global_load_lds(                                     \
          (const __attribute__((address_space(1))) unsigned*)g_,            \
          (__attribute__((address_space(3))) unsigned*)(smem[b] +           \
                                                        q_ * 1024),         \
          16, 0, 0);                                                        \
    }                                                                       \
  }

  const int nt = NN / 64;  // 48
  STAGE(0, 0);
  STAGE(1, 1);
  for (int kt = 0; kt < nt; ++kt) {
    // wait own stage-kt loads (6); stage kt+1 (6) stays in flight
    if (kt < nt - 1) {
      asm volatile("s_waitcnt vmcnt(6)" ::: "memory");
    } else {
      asm volatile("s_waitcnt vmcnt(0)" ::: "memory");
    }
    __builtin_amdgcn_s_barrier();
    __builtin_amdgcn_sched_barrier(0);
    const char* sb = smem[kt % 3];
    i32x8 af[3], bfr[3];
#pragma unroll
    for (int i = 0; i < 3; ++i)
      af[i] = ldfragL(sb + (wr * 3 + i) * 2048 + l * 16);
#pragma unroll
    for (int j = 0; j < 3; ++j)
      bfr[j] = ldfragL(sb + 12288 + (wc * 3 + j) * 2048 + l * 16);
    if (kt + 2 < nt) STAGE(kt + 2, (kt + 2) % 3);
    __builtin_amdgcn_s_setprio(1);
#pragma unroll
    for (int i = 0; i < 3; ++i)
#pragma unroll
      for (int j = 0; j < 3; ++j)
        acc[i][j] = __builtin_amdgcn_mfma_scale_f32_32x32x64_f8f6f4(
            af[i], bfr[j], acc[i][j], 0, 0, 0, 127, 0, 127);
    __builtin_amdgcn_s_setprio(0);
    __builtin_amdgcn_sched_barrier(0);
  }
#undef STAGE

  // C/D 32x32 layout: col = lane&31, row = (reg&3) + 8*(reg>>2) + 4*(lane>>5)
#pragma unroll
  for (int i = 0; i < 3; ++i) {
    int rb = rowBase + wr * 96 + i * 32 + 4 * hh;
#pragma unroll
    for (int j = 0; j < 3; ++j) {
      int cc = colBase + wc * 96 + j * 32 + r32;
#pragma unroll
      for (int reg = 0; reg < 16; ++reg) {
        int rr = rb + (reg & 3) + 8 * (reg >> 2);
        Cg[(size_t)rr * NN + cc] = bf16bits(acc[i][j][reg]);
      }
    }
  }
}

// ---------------------------------------------------------------------------
// post1: [0,768)     topk(A2 bf16) + packed fp8 cast -> A2f8
//        [768,1536)  tvec = A.y1 (one wave per row)
__global__ __launch_bounds__(256) void post1(
    const unsigned short* __restrict__ C, int parts,
    const float* __restrict__ A, const float* __restrict__ y1,
    unsigned char* __restrict__ A2f8, int* __restrict__ cnts1,
    int* __restrict__ tIdx1, float* __restrict__ tVal1,
    float* __restrict__ tvec) {
  const int bid = blockIdx.x;
  const int t = threadIdx.x;
  if (bid < 768) {
    int row = bid * 4 + (t >> 6);
    int lane = t & 63;
    float f[48];
    load48_bf(C, parts, row, lane, f);
    // fused packed fp8 cast: f[j*8+e] = col k0+e, k0=(j*64+lane)*8
#pragma unroll
    for (int j = 0; j < 6; ++j) {
      uint2 w;
      w.x = pk4_f8(f[j * 8 + 0] * F8SCALE2, f[j * 8 + 1] * F8SCALE2,
                   f[j * 8 + 2] * F8SCALE2, f[j * 8 + 3] * F8SCALE2);
      w.y = pk4_f8(f[j * 8 + 4] * F8SCALE2, f[j * 8 + 5] * F8SCALE2,
                   f[j * 8 + 6] * F8SCALE2, f[j * 8 + 7] * F8SCALE2);
      size_t addr = (size_t)(j * 8 + (lane >> 3)) * KBLK +
                    (size_t)row * 64 + (lane & 7) * 8;
      *(uint2*)(A2f8 + addr) = w;
    }
    select_compact(f, lane, DESCALE38, 1, &cnts1[row],
                   tIdx1 + (size_t)row * 128, tVal1 + (size_t)row * 128);
  } else {
    int row = (bid - 768) * 4 + (t >> 6);
    int lane = t & 63;
    const float4* rp = (const float4*)(A + (size_t)row * NN);
    const float4* yp = (const float4*)y1;
    float s = 0.f;
#pragma unroll
    for (int j = 0; j < 12; ++j) {
      float4 a = rp[lane + j * 64];
      float4 y = yp[lane + j * 64];
      s += a.x * y.x + a.y * y.y + a.z * y.z + a.w * y.w;
    }
    for (int off = 32; off; off >>= 1) s += __shfl_down(s, off, 64);
    if (lane == 0) tvec[row] = s;
  }
}

// ---------------------------------------------------------------------------
// sel02: phase-homogeneous select kernel (one select per wave, dense waves).
//   bid < 1536, even: layer-2 lists from C (A3 bf16) -> global
//   bid < 1536, odd:  layer-0 lists from A (fp32)    -> global
//   bid == 1536:      post2 fold (w0..w3 -> wacc)
__global__ __launch_bounds__(256) void sel02(
    const unsigned short* __restrict__ C, int parts,
    const float* __restrict__ A, int* __restrict__ cnt0,
    int* __restrict__ idx0, float* __restrict__ val0,
    int* __restrict__ cnt2, int* __restrict__ idx2,
    float* __restrict__ val2, const float* __restrict__ vu,
    const float* __restrict__ vv, const float* __restrict__ y1,
    const float* __restrict__ s1, const float* __restrict__ tvec,
    float* __restrict__ wacc) {
  __shared__ float red4[4];
  const int bid = blockIdx.x;
  const int t = threadIdx.x;
  if (bid == 1536) {
    float w0 = row_dot_f32(vu, vv, red4);  __syncthreads();
    float w1 = row_dot_f32(vu, y1, red4);  __syncthreads();
    float w2 = row_dot_f32(s1, y1, red4);  __syncthreads();
    float w3 = row_dot_f32(s1, tvec, red4);
    if (t == 0) { wacc[0] = w0; wacc[1] = w1; wacc[2] = w2; wacc[3] = w3; }
    return;
  }
  const int w = t >> 6, lane = t & 63;
  const int row = (bid >> 1) * 4 + w;
  float f[48];
  if ((bid & 1) == 0) {
    load48_bf(C, parts, row, lane, f);
    select_compact(f, lane, DESCALE38, 1, &cnt2[row],
                   idx2 + (size_t)row * 128, val2 + (size_t)row * 128);
  } else {
    load48_f32(A, row, lane, f);
    select_compact(f, lane, 1.0f, 0, &cnt0[row],
                   idx0 + (size_t)row * 128, val0 + (size_t)row * 128);
  }
}

// ---------------------------------------------------------------------------
// gather_light: pure gather, one wave per row (768 blocks x 256 thr).
__global__ __launch_bounds__(256) void gather_light(
    const float* __restrict__ allE, const float* __restrict__ uemb0,
    const float* __restrict__ iemb0, const float* __restrict__ wacc,
    const int* __restrict__ cnt0, const int* __restrict__ idx0,
    const float* __restrict__ val0, const int* __restrict__ cnts1,
    const int* __restrict__ tIdx1, const float* __restrict__ tVal1,
    const int* __restrict__ cnt2, const int* __restrict__ idx2,
    const float* __restrict__ val2, float* __restrict__ lightOut) {
  __shared__ int li[4][384];
  __shared__ float lv[4][384];
  const int t = threadIdx.x;
  const int w = t >> 6, lane = t & 63;
  const int row = blockIdx.x * 4 + w;

  float w0 = wacc[0], w1 = wacc[1], w2 = wacc[2], w3 = wacc[3];
  float ss = w0 + w1 + w2 + w3;
  w0 /= ss; w1 /= ss; w2 /= ss; w3 /= ss;
  float m = fmaxf(fmaxf(w0, w1), fmaxf(w2, w3));
  float ex0 = expf(w0 - m), ex1 = expf(w1 - m), ex2 = expf(w2 - m),
        ex3 = expf(w3 - m);
  float se = ex0 + ex1 + ex2 + ex3;
  float aw0 = ex0 / se, aw1 = ex1 / se, aw2 = ex2 / se, aw3 = ex3 / se;
  float aw4 = GAMMA_F * (aw1 + aw2 + aw3);

  const int c0 = cnt0[row], c1 = cnts1[row], c2 = cnt2[row];
  const int p0 = (c0 + 7) & ~7, p1 = (c1 + 7) & ~7, p2 = (c2 + 7) & ~7;
  int* Li = li[w];
  float* Lv = lv[w];
  const size_t rb = (size_t)row * 128;
  for (int k = lane; k < p0; k += 64) {
    bool in = k < c0;
    Li[k] = in ? idx0[rb + k] : 0;
    Lv[k] = in ? aw1 * val0[rb + k] : 0.f;
  }
  for (int k = lane; k < p1; k += 64) {
    bool in = k < c1;
    Li[p0 + k] = in ? tIdx1[rb + k] : 0;
    Lv[p0 + k] = in ? aw2 * tVal1[rb + k] : 0.f;
  }
  for (int k = lane; k < p2; k += 64) {
    bool in = k < c2;
    Li[p0 + p1 + k] = in ? idx2[rb + k] : 0;
    Lv[p0 + p1 + k] = in ? aw3 * val2[rb + k] : 0.f;
  }
  // same-wave produce->consume through LDS: compiler orders via lgkmcnt.

  const int ct = p0 + p1 + p2;
  const float2* E2 = (const float2*)allE;
  float ax = 0.f, ay = 0.f, bx_ = 0.f, by_ = 0.f;
  for (int k = 0; k < ct; k += 8) {
    int i0 = Li[k + 0], i1 = Li[k + 1], i2 = Li[k + 2], i3 = Li[k + 3];
    int i4 = Li[k + 4], i5 = Li[k + 5], i6 = Li[k + 6], i7 = Li[k + 7];
    float v0 = Lv[k + 0], v1 = Lv[k + 1], v2 = Lv[k + 2], v3 = Lv[k + 3];
    float v4 = Lv[k + 4], v5 = Lv[k + 5], v6 = Lv[k + 6], v7 = Lv[k + 7];
    float2 g0 = E2[(i0 >> 1) + lane];
    float2 g1 = E2[(i1 >> 1) + lane];
    float2 g2 = E2[(i2 >> 1) + lane];
    float2 g3 = E2[(i3 >> 1) + lane];
    float2 g4 = E2[(i4 >> 1) + lane];
    float2 g5 = E2[(i5 >> 1) + lane];
    float2 g6 = E2[(i6 >> 1) + lane];
    float2 g7 = E2[(i7 >> 1) + lane];
    ax += v0 * g0.x; ay += v0 * g0.y;
    bx_ += v1 * g1.x; by_ += v1 * g1.y;
    ax += v2 * g2.x; ay += v2 * g2.y;
    bx_ += v3 * g3.x; by_ += v3 * g3.y;
    ax += v4 * g4.x; ay += v4 * g4.y;
    bx_ += v5 * g5.x; by_ += v5 * g5.y;
    ax += v6 * g6.x; ay += v6 * g6.y;
    bx_ += v7 * g7.x; by_ += v7 * g7.y;
  }
  float2 sE = E2[((size_t)row << 6) + lane];
  float2 e0 = (row < NU)
                  ? ((const float2*)uemb0)[(size_t)row * 64 + lane]
                  : ((const float2*)iemb0)[(size_t)(row - NU) * 64 + lane];
  float ox = (ax + bx_) + aw0 * sE.x + aw4 * e0.x;
  float oy = (ay + by_) + aw0 * sE.y + aw4 * e0.y;
  float2 o; o.x = ox; o.y = oy;
  ((float2*)lightOut)[(size_t)row * 64 + lane] = o;
}

__global__ __launch_bounds__(256) void out_dot(const int* __restrict__ users,
                                               const int* __restrict__ items,
                                               const float* __restrict__ lightOut,
                                               float* __restrict__ out) {
  int b = blockIdx.x * 4 + (threadIdx.x >> 6);
  int lane = threadIdx.x & 63;
  const float* up = lightOut + (size_t)users[b] * DD;
  const float* ip = lightOut + (size_t)(NU + items[b]) * DD;
  float s = up[lane] * ip[lane] + up[lane + 64] * ip[lane + 64];
  for (int off = 32; off; off >>= 1) s += __shfl_down(s, off, 64);
  if (lane == 0) out[b] = s;
}

// ---------------------------------------------------------------------------
extern "C" void kernel_launch(void* const* d_in, const int* in_sizes, int n_in,
                              void* d_out, int out_size, void* d_ws,
                              size_t ws_size, hipStream_t stream) {
  const int* users = (const int*)d_in[0];
  const int* items = (const int*)d_in[1];
  const float* A = (const float*)d_in[2];
  const float* uemb = (const float*)d_in[3];
  const float* iemb = (const float*)d_in[4];
  const float* uemb0 = (const float*)d_in[5];
  const float* iemb0 = (const float*)d_in[6];
  const float* vu = (const float*)d_in[7];
  const float* vv = (const float*)d_in[8];
  float* out = (float*)d_out;

  char* ws = (char*)d_ws;
  size_t off = 0;
  auto alloc = [&](size_t bytes) -> void* {
    void* p = ws + off;
    off += (bytes + 255) & ~(size_t)255;
    return p;
  };
  unsigned char* Af8 = (unsigned char*)alloc((size_t)NN * NN);
  unsigned char* Atf8 = (unsigned char*)alloc((size_t)NN * NN);
  unsigned char* A2f8 = (unsigned char*)alloc((size_t)NN * NN);
  float* y1 = (float*)alloc((size_t)NN * 4);   // contiguous with s1
  float* s1 = (float*)alloc((size_t)NN * 4);
  float* tvec = (float*)alloc((size_t)NN * 4);
  float* wacc = (float*)alloc(256);
  int* cnts1 = (int*)alloc((size_t)NN * 4);
  int* tIdx1 = (int*)alloc((size_t)NN * 128 * 4);
  float* tVal1 = (float*)alloc((size_t)NN * 128 * 4);
  float* lightOut = (float*)alloc((size_t)NN * DD * 4);
  int* cnt0 = (int*)alloc((size_t)NN * 4);
  int* cnt2 = (int*)alloc((size_t)NN * 4);
  float* allE = (float*)alloc((size_t)NN * DD * 4);  // dedicated (no alias)

  // layer-0/2 lists (4 x 1.5 MB) alias Atf8 (9.4 MB): Atf8 is dead after
  // gemm#2 (step 5); sel02 (step 6) writes, gather (step 8) reads.
  const size_t LSTB = (size_t)NN * 128 * 4;
  int* idx0 = (int*)(Atf8);
  float* val0 = (float*)(Atf8 + LSTB);
  int* idx2 = (int*)(Atf8 + 2 * LSTB);
  float* val2 = (float*)(Atf8 + 3 * LSTB);

  // single-part bf16 C
  unsigned short* C = (unsigned short*)alloc((size_t)NN * NN * 2);

  // 1) zero y1/s1 (contiguous 2*NN floats)
  hipMemsetAsync(y1, 0, (size_t)2 * NN * 4, stream);
  // 2) prep: A -> packed fp8 (straight+transposed) + y1/s1 | emb concat
  prep<<<2688, 256, 0, stream>>>(A, vu, vv, Af8, Atf8, y1, s1, uemb, iemb,
                                 allE);
  // 3) A2 = A*A (192-tile 3x3-wave pipelined MX fp8 MFMA, grid 256 = 1/CU)
  gemm_f8<<<256, 256, 0, stream>>>(Af8, Atf8, C);
  // 4) post1: topk(A2)+packed fp8 cast | tvec = A.y1
  post1<<<1536, 256, 0, stream>>>(C, 1, A, y1, A2f8, cnts1, tIdx1, tVal1,
                                  tvec);
  // 5) A3 = A2*A (overwrite C)
  gemm_f8<<<256, 256, 0, stream>>>(A2f8, Atf8, C);
  // 6) sel02: layer-0 (A) + layer-2 (A3) top-64 lists | post2 fold (bid 1536)
  sel02<<<1537, 256, 0, stream>>>(C, 1, A, cnt0, idx0, val0, cnt2, idx2,
                                  val2, vu, vv, y1, s1, tvec, wacc);
  // 7) gather_light: pure float2 gather, one wave per row
  gather_light<<<768, 256, 0, stream>>>(allE, uemb0, iemb0, wacc, cnt0, idx0,
                                        val0, cnts1, tIdx1, tVal1, cnt2, idx2,
                                        val2, lightOut);
  // 8) gather dots
  out_dot<<<BB / 4, 256, 0, stream>>>(users, items, lightOut, out);
}